// Round 1
// baseline (1274.447 us; speedup 1.0000x reference)
//
#include <hip/hip_runtime.h>
#include <math.h>

typedef unsigned short u16;
typedef unsigned int   u32;
typedef __attribute__((ext_vector_type(8))) short bf16x8;  // 8 bf16 (4 VGPRs)
typedef __attribute__((ext_vector_type(4))) float f32x4;

__device__ __forceinline__ u16 f2bf(float f) {
  u32 u = __builtin_bit_cast(u32, f);
  u += 0x7fffu + ((u >> 16) & 1u);   // RNE
  return (u16)(u >> 16);
}

// ---------------- transpose + convert: W[K][N] f32 -> Wt[N][K] bf16 ----------
__global__ __launch_bounds__(256)
void transcvt_kernel(const float* __restrict__ W, u16* __restrict__ Wt, int K, int N) {
  __shared__ float tile[32][33];
  const int n0 = blockIdx.x * 32, k0 = blockIdx.y * 32;
  const int tx = threadIdx.x & 31, ty = threadIdx.x >> 5;  // 32 x 8
  for (int i = 0; i < 4; ++i)
    tile[ty + 8 * i][tx] = W[(size_t)(k0 + ty + 8 * i) * N + n0 + tx];
  __syncthreads();
  for (int i = 0; i < 4; ++i)
    Wt[(size_t)(n0 + ty + 8 * i) * K + k0 + tx] = f2bf(tile[tx][ty + 8 * i]);
}

// ---------------- elementwise convert f32 -> bf16 ----------------------------
__global__ __launch_bounds__(256)
void cvt_kernel(const float* __restrict__ in, u16* __restrict__ out) {
  const int i = blockIdx.x * 256 + threadIdx.x;
  const float4 v = ((const float4*)in)[i];
  u16 o[4] = {f2bf(v.x), f2bf(v.y), f2bf(v.z), f2bf(v.w)};
  ((ushort4*)out)[i] = *(ushort4*)o;
}

// ---------------- LayerNorm: rows of 1024, f32 in -> bf16 out ---------------
__global__ __launch_bounds__(256)
void ln_kernel(const float* __restrict__ x, const float* __restrict__ g,
               const float* __restrict__ b, u16* __restrict__ out) {
  const int row = blockIdx.x;
  const float4 v4 = ((const float4*)(x + (size_t)row * 1024))[threadIdx.x];
  float vv[4] = {v4.x, v4.y, v4.z, v4.w};
  float s = vv[0] + vv[1] + vv[2] + vv[3];
  float s2 = vv[0] * vv[0] + vv[1] * vv[1] + vv[2] * vv[2] + vv[3] * vv[3];
  for (int m = 1; m < 64; m <<= 1) { s += __shfl_xor(s, m); s2 += __shfl_xor(s2, m); }
  __shared__ float ss[4], ss2[4];
  const int w = threadIdx.x >> 6;
  if ((threadIdx.x & 63) == 0) { ss[w] = s; ss2[w] = s2; }
  __syncthreads();
  s = ss[0] + ss[1] + ss[2] + ss[3];
  s2 = ss2[0] + ss2[1] + ss2[2] + ss2[3];
  const float mu = s * (1.0f / 1024.0f);
  const float var = s2 * (1.0f / 1024.0f) - mu * mu;
  const float r = rsqrtf(var + 1e-5f);
  const int c = threadIdx.x * 4;
  const float4 g4 = ((const float4*)g)[threadIdx.x];
  const float4 b4 = ((const float4*)b)[threadIdx.x];
  float gg[4] = {g4.x, g4.y, g4.z, g4.w};
  float bb[4] = {b4.x, b4.y, b4.z, b4.w};
  u16 o[4];
  for (int j = 0; j < 4; ++j) o[j] = f2bf((vv[j] - mu) * r * gg[j] + bb[j]);
  ((ushort4*)(out + (size_t)row * 1024 + c))[0] = *(ushort4*)o;
}

// ---------------- GEMM: C[M,N] = act(A[M,K] @ Bt[N,K]^T + bias) (+res) ------
// A, Bt bf16; bias f32 (nullable). RES_F32: out f32 = res + val; else out bf16.
template<bool RES_F32, bool GELU>
__global__ __launch_bounds__(256)
void gemm_kernel(const u16* __restrict__ A, const u16* __restrict__ Bt,
                 const float* __restrict__ bias, const float* __restrict__ res,
                 void* __restrict__ Cout, int M, int N, int K) {
  __shared__ u16 As[128][32];
  __shared__ u16 Bs[128][32];
  const int t = threadIdx.x;
  const int lane = t & 63, w = t >> 6;
  const int wr = w >> 1, wc = w & 1;
  const int m0 = blockIdx.y * 128, n0 = blockIdx.x * 128;
  const int lr = t >> 2, lc = (t & 3) * 8;
  const int fr = lane & 15, fg = lane >> 4;
  f32x4 acc[4][4] = {};
  for (int k0 = 0; k0 < K; k0 += 32) {
    for (int it = 0; it < 2; ++it) {
      const int r = lr + it * 64;
      *(bf16x8*)&As[r][lc] = *(const bf16x8*)&A[(size_t)(m0 + r) * K + k0 + lc];
      *(bf16x8*)&Bs[r][lc] = *(const bf16x8*)&Bt[(size_t)(n0 + r) * K + k0 + lc];
    }
    __syncthreads();
    bf16x8 af[4], bfr[4];
    for (int m = 0; m < 4; ++m) af[m] = *(bf16x8*)&As[wr * 64 + m * 16 + fr][fg * 8];
    for (int n = 0; n < 4; ++n) bfr[n] = *(bf16x8*)&Bs[wc * 64 + n * 16 + fr][fg * 8];
    for (int m = 0; m < 4; ++m)
      for (int n = 0; n < 4; ++n)
        acc[m][n] = __builtin_amdgcn_mfma_f32_16x16x32_bf16(af[m], bfr[n], acc[m][n], 0, 0, 0);
    __syncthreads();
  }
  for (int m = 0; m < 4; ++m)
    for (int n = 0; n < 4; ++n) {
      const int col = n0 + wc * 64 + n * 16 + fr;
      const float bv = bias ? bias[col] : 0.0f;
      for (int i = 0; i < 4; ++i) {
        const int row = m0 + wr * 64 + m * 16 + fg * 4 + i;
        float v = acc[m][n][i] + bv;
        if (GELU) v = 0.5f * v * (1.0f + erff(v * 0.70710678118654752f));
        if (RES_F32)
          ((float*)Cout)[(size_t)row * N + col] = res[(size_t)row * N + col] + v;
        else
          ((u16*)Cout)[(size_t)row * N + col] = f2bf(v);
      }
    }
}

// ---------------- Flash attention: Q,K,V bf16 [4096][1024] per-head ---------
// grid (T/64, B*H), 256 thr (4 waves x 16 q-rows). 32-key tiles, online softmax.
template<bool CAUSAL>
__global__ __launch_bounds__(256)
void attn_kernel(const u16* __restrict__ Q, const u16* __restrict__ K,
                 const u16* __restrict__ V, u16* __restrict__ O) {
  __shared__ u16 Vs[32][64];
  __shared__ u16 Ps[4][16][32];
  const int bh = blockIdx.y, b = bh >> 4, h = bh & 15;
  const int q0 = blockIdx.x * 64;
  const int w = threadIdx.x >> 6, lane = threadIdx.x & 63;
  const int fr = lane & 15, fg = lane >> 4;
  const int qr = q0 + w * 16;
  const int hcol = h * 64;
  const size_t qrow = (size_t)(b * 1024 + qr + fr);
  bf16x8 qf[2];
  qf[0] = *(const bf16x8*)&Q[qrow * 1024 + hcol + fg * 8];
  qf[1] = *(const bf16x8*)&Q[qrow * 1024 + hcol + 32 + fg * 8];
  f32x4 o[4] = {};
  float mrow[4], lrow[4] = {};
  for (int i = 0; i < 4; ++i) mrow[i] = -1e30f;
  const int nkt = CAUSAL ? (q0 / 32 + 2) : 32;
  for (int kt = 0; kt < nkt; ++kt) {
    const int k0 = kt * 32;
    {
      const int vr = threadIdx.x >> 3, vc = (threadIdx.x & 7) * 8;
      *(bf16x8*)&Vs[vr][vc] =
          *(const bf16x8*)&V[(size_t)(b * 1024 + k0 + vr) * 1024 + hcol + vc];
    }
    __syncthreads();
    f32x4 s0 = {}, s1 = {};
    for (int kk = 0; kk < 2; ++kk) {
      const bf16x8 kf0 = *(const bf16x8*)&K[(size_t)(b * 1024 + k0 + fr) * 1024 + hcol + kk * 32 + fg * 8];
      const bf16x8 kf1 = *(const bf16x8*)&K[(size_t)(b * 1024 + k0 + 16 + fr) * 1024 + hcol + kk * 32 + fg * 8];
      s0 = __builtin_amdgcn_mfma_f32_16x16x32_bf16(qf[kk], kf0, s0, 0, 0, 0);
      s1 = __builtin_amdgcn_mfma_f32_16x16x32_bf16(qf[kk], kf1, s1, 0, 0, 0);
    }
    float p0[4], p1[4], rm[4];
    for (int i = 0; i < 4; ++i) {
      float a = s0[i] * 0.125f, c = s1[i] * 0.125f;
      if (CAUSAL) {
        const int myq = qr + fg * 4 + i;
        if (k0 + fr > myq) a = -1e30f;
        if (k0 + 16 + fr > myq) c = -1e30f;
      }
      p0[i] = a; p1[i] = c;
      rm[i] = fmaxf(a, c);
    }
    for (int off = 1; off < 16; off <<= 1)
      for (int i = 0; i < 4; ++i) rm[i] = fmaxf(rm[i], __shfl_xor(rm[i], off));
    float rs[4];
    for (int i = 0; i < 4; ++i) {
      const float mn = fmaxf(mrow[i], rm[i]);
      const float sc = __expf(mrow[i] - mn);
      p0[i] = __expf(p0[i] - mn);
      p1[i] = __expf(p1[i] - mn);
      mrow[i] = mn;
      lrow[i] *= sc;
      rs[i] = p0[i] + p1[i];
      for (int nb = 0; nb < 4; ++nb) o[nb][i] *= sc;
    }
    for (int off = 1; off < 16; off <<= 1)
      for (int i = 0; i < 4; ++i) rs[i] += __shfl_xor(rs[i], off);
    for (int i = 0; i < 4; ++i) {
      lrow[i] += rs[i];
      Ps[w][fg * 4 + i][fr] = f2bf(p0[i]);
      Ps[w][fg * 4 + i][16 + fr] = f2bf(p1[i]);
    }
    __syncthreads();
    const bf16x8 pa = *(bf16x8*)&Ps[w][fr][fg * 8];
    for (int nb = 0; nb < 4; ++nb) {
      bf16x8 vb;
      for (int j = 0; j < 8; ++j) ((u16*)&vb)[j] = Vs[fg * 8 + j][nb * 16 + fr];
      o[nb] = __builtin_amdgcn_mfma_f32_16x16x32_bf16(pa, vb, o[nb], 0, 0, 0);
    }
    __syncthreads();
  }
  for (int i = 0; i < 4; ++i) {
    const float inv = 1.0f / lrow[i];
    const size_t row = (size_t)(b * 1024 + qr + fg * 4 + i);
    for (int nb = 0; nb < 4; ++nb)
      O[row * 1024 + hcol + nb * 16 + fr] = f2bf(o[nb][i] * inv);
  }
}

// ---------------------------------------------------------------------------
extern "C" void kernel_launch(void* const* d_in, const int* in_sizes, int n_in,
                              void* d_out, int out_size, void* d_ws, size_t ws_size,
                              hipStream_t stream) {
  const float* dec  = (const float*)d_in[0];
  const float* enc  = (const float*)d_in[1];
  const float* sa_g = (const float*)d_in[4];
  const float* sa_b = (const float*)d_in[5];
  const float* sa_wq = (const float*)d_in[6];
  const float* sa_bq = (const float*)d_in[7];
  const float* sa_wk = (const float*)d_in[8];
  const float* sa_wv = (const float*)d_in[9];
  const float* sa_bv = (const float*)d_in[10];
  const float* sa_wo = (const float*)d_in[11];
  const float* sa_bo = (const float*)d_in[12];
  const float* ca_g = (const float*)d_in[13];
  const float* ca_b = (const float*)d_in[14];
  const float* ca_wq = (const float*)d_in[15];
  const float* ca_bq = (const float*)d_in[16];
  const float* ca_wk = (const float*)d_in[17];
  const float* ca_wv = (const float*)d_in[18];
  const float* ca_bv = (const float*)d_in[19];
  const float* ca_wo = (const float*)d_in[20];
  const float* ca_bo = (const float*)d_in[21];
  const float* mlp_g = (const float*)d_in[22];
  const float* mlp_b = (const float*)d_in[23];
  const float* w1 = (const float*)d_in[24];
  const float* b1 = (const float*)d_in[25];
  const float* w2 = (const float*)d_in[26];
  const float* b2 = (const float*)d_in[27];

  const size_t MB = 1024 * 1024;
  if (ws_size < 112 * MB) return;
  char* ws = (char*)d_ws;
  u16* WQT = (u16*)(ws + 0 * MB);
  u16* WKT = (u16*)(ws + 2 * MB);
  u16* WVT = (u16*)(ws + 4 * MB);
  u16* WOT = (u16*)(ws + 6 * MB);
  u16* CQT = (u16*)(ws + 8 * MB);
  u16* CKT = (u16*)(ws + 10 * MB);
  u16* CVT = (u16*)(ws + 12 * MB);
  u16* COT = (u16*)(ws + 14 * MB);
  u16* W1T = (u16*)(ws + 16 * MB);   // [4096][1024]
  u16* W2T = (u16*)(ws + 24 * MB);   // [1024][4096]
  u16* ENC = (u16*)(ws + 32 * MB);
  u16* XLN = (u16*)(ws + 40 * MB);
  u16* QB  = (u16*)(ws + 48 * MB);
  u16* KB  = (u16*)(ws + 56 * MB);
  u16* VB  = (u16*)(ws + 64 * MB);
  u16* AO  = (u16*)(ws + 72 * MB);
  float* X1 = (float*)(ws + 80 * MB);
  float* X2 = (float*)(ws + 96 * MB);
  u16* H1  = (u16*)(ws + 48 * MB);   // aliases QB..AO (dead by FFN stage)
  float* OUT = (float*)d_out;

  const dim3 blk(256);
  // weights: transpose + convert
  transcvt_kernel<<<dim3(32, 32), blk, 0, stream>>>(sa_wq, WQT, 1024, 1024);
  transcvt_kernel<<<dim3(32, 32), blk, 0, stream>>>(sa_wk, WKT, 1024, 1024);
  transcvt_kernel<<<dim3(32, 32), blk, 0, stream>>>(sa_wv, WVT, 1024, 1024);
  transcvt_kernel<<<dim3(32, 32), blk, 0, stream>>>(sa_wo, WOT, 1024, 1024);
  transcvt_kernel<<<dim3(32, 32), blk, 0, stream>>>(ca_wq, CQT, 1024, 1024);
  transcvt_kernel<<<dim3(32, 32), blk, 0, stream>>>(ca_wk, CKT, 1024, 1024);
  transcvt_kernel<<<dim3(32, 32), blk, 0, stream>>>(ca_wv, CVT, 1024, 1024);
  transcvt_kernel<<<dim3(32, 32), blk, 0, stream>>>(ca_wo, COT, 1024, 1024);
  transcvt_kernel<<<dim3(128, 32), blk, 0, stream>>>(w1, W1T, 1024, 4096);
  transcvt_kernel<<<dim3(32, 128), blk, 0, stream>>>(w2, W2T, 4096, 1024);
  cvt_kernel<<<dim3(4096), blk, 0, stream>>>(enc, ENC);

  const dim3 g1k(8, 32);   // N=1024
  const dim3 g4k(32, 32);  // N=4096

  // ---- self-attention block ----
  ln_kernel<<<dim3(4096), blk, 0, stream>>>(dec, sa_g, sa_b, XLN);
  gemm_kernel<false, false><<<g1k, blk, 0, stream>>>(XLN, WQT, sa_bq, nullptr, QB, 4096, 1024, 1024);
  gemm_kernel<false, false><<<g1k, blk, 0, stream>>>(XLN, WKT, nullptr, nullptr, KB, 4096, 1024, 1024);
  gemm_kernel<false, false><<<g1k, blk, 0, stream>>>(XLN, WVT, sa_bv, nullptr, VB, 4096, 1024, 1024);
  attn_kernel<true><<<dim3(16, 64), blk, 0, stream>>>(QB, KB, VB, AO);
  gemm_kernel<true, false><<<g1k, blk, 0, stream>>>(AO, WOT, sa_bo, dec, X1, 4096, 1024, 1024);

  // ---- cross-attention block ----
  ln_kernel<<<dim3(4096), blk, 0, stream>>>(X1, ca_g, ca_b, XLN);
  gemm_kernel<false, false><<<g1k, blk, 0, stream>>>(XLN, CQT, ca_bq, nullptr, QB, 4096, 1024, 1024);
  gemm_kernel<false, false><<<g1k, blk, 0, stream>>>(ENC, CKT, nullptr, nullptr, KB, 4096, 1024, 1024);
  gemm_kernel<false, false><<<g1k, blk, 0, stream>>>(ENC, CVT, ca_bv, nullptr, VB, 4096, 1024, 1024);
  attn_kernel<false><<<dim3(16, 64), blk, 0, stream>>>(QB, KB, VB, AO);
  gemm_kernel<true, false><<<g1k, blk, 0, stream>>>(AO, COT, ca_bo, X1, X2, 4096, 1024, 1024);

  // ---- FFN block ----
  ln_kernel<<<dim3(4096), blk, 0, stream>>>(X2, mlp_g, mlp_b, XLN);
  gemm_kernel<false, true><<<g4k, blk, 0, stream>>>(XLN, W1T, b1, nullptr, H1, 4096, 4096, 1024);
  gemm_kernel<true, false><<<g1k, blk, 0, stream>>>(H1, W2T, b2, X2, OUT, 4096, 1024, 4096);
}

// Round 2
// 1215.296 us; speedup vs baseline: 1.0487x; 1.0487x over previous
//
#include <hip/hip_runtime.h>
#include <math.h>

typedef unsigned short u16;
typedef unsigned int   u32;
typedef __attribute__((ext_vector_type(8))) short bf16x8;  // 8 bf16 (4 VGPRs)
typedef __attribute__((ext_vector_type(4))) float f32x4;

__device__ __forceinline__ u16 f2bf(float f) {
  u32 u = __builtin_bit_cast(u32, f);
  u += 0x7fffu + ((u >> 16) & 1u);   // RNE
  return (u16)(u >> 16);
}

// async global->LDS, 16B per lane. LDS dest must be wave-uniform; HW writes
// lane l's 16B at dest + l*16 (linear). Global src is per-lane.
__device__ __forceinline__ void g2l16(const u16* g, u16* l) {
  __builtin_amdgcn_global_load_lds(
      (const __attribute__((address_space(1))) unsigned int*)g,
      (__attribute__((address_space(3))) unsigned int*)l, 16, 0, 0);
}

// ---------------- transpose + convert: W[K][N] f32 -> Wt[N][K] bf16 ----------
__global__ __launch_bounds__(256)
void transcvt_kernel(const float* __restrict__ W, u16* __restrict__ Wt, int K, int N) {
  __shared__ float tile[32][33];
  const int n0 = blockIdx.x * 32, k0 = blockIdx.y * 32;
  const int tx = threadIdx.x & 31, ty = threadIdx.x >> 5;  // 32 x 8
  for (int i = 0; i < 4; ++i)
    tile[ty + 8 * i][tx] = W[(size_t)(k0 + ty + 8 * i) * N + n0 + tx];
  __syncthreads();
  for (int i = 0; i < 4; ++i)
    Wt[(size_t)(n0 + ty + 8 * i) * K + k0 + tx] = f2bf(tile[tx][ty + 8 * i]);
}

// ---------------- elementwise convert f32 -> bf16 ----------------------------
__global__ __launch_bounds__(256)
void cvt_kernel(const float* __restrict__ in, u16* __restrict__ out) {
  const int i = blockIdx.x * 256 + threadIdx.x;
  const float4 v = ((const float4*)in)[i];
  u16 o[4] = {f2bf(v.x), f2bf(v.y), f2bf(v.z), f2bf(v.w)};
  ((ushort4*)out)[i] = *(ushort4*)o;
}

// ---------------- bias packing ----------------------------------------------
// dst[0:1024)=bq, [1024:2048)=0, [2048:3072)=bv
__global__ __launch_bounds__(256)
void pack_bias3_kernel(const float* __restrict__ bq, const float* __restrict__ bv,
                       float* __restrict__ dst) {
  const int i = blockIdx.x * 256 + threadIdx.x;
  float v = 0.0f;
  if (i < 1024) v = bq[i];
  else if (i >= 2048) v = bv[i - 2048];
  dst[i] = v;
}
// dst[0:1024)=0 (k), [1024:2048)=bv
__global__ __launch_bounds__(256)
void pack_bias2_kernel(const float* __restrict__ bv, float* __restrict__ dst) {
  const int i = blockIdx.x * 256 + threadIdx.x;
  dst[i] = (i >= 1024) ? bv[i - 1024] : 0.0f;
}

// ---------------- LayerNorm: rows of 1024, f32 in -> bf16 out ---------------
__global__ __launch_bounds__(256)
void ln_kernel(const float* __restrict__ x, const float* __restrict__ g,
               const float* __restrict__ b, u16* __restrict__ out) {
  const int row = blockIdx.x;
  const float4 v4 = ((const float4*)(x + (size_t)row * 1024))[threadIdx.x];
  float vv[4] = {v4.x, v4.y, v4.z, v4.w};
  float s = vv[0] + vv[1] + vv[2] + vv[3];
  float s2 = vv[0] * vv[0] + vv[1] * vv[1] + vv[2] * vv[2] + vv[3] * vv[3];
  for (int m = 1; m < 64; m <<= 1) { s += __shfl_xor(s, m); s2 += __shfl_xor(s2, m); }
  __shared__ float ss[4], ss2[4];
  const int w = threadIdx.x >> 6;
  if ((threadIdx.x & 63) == 0) { ss[w] = s; ss2[w] = s2; }
  __syncthreads();
  s = ss[0] + ss[1] + ss[2] + ss[3];
  s2 = ss2[0] + ss2[1] + ss2[2] + ss2[3];
  const float mu = s * (1.0f / 1024.0f);
  const float var = s2 * (1.0f / 1024.0f) - mu * mu;
  const float r = rsqrtf(var + 1e-5f);
  const int c = threadIdx.x * 4;
  const float4 g4 = ((const float4*)g)[threadIdx.x];
  const float4 b4 = ((const float4*)b)[threadIdx.x];
  float gg[4] = {g4.x, g4.y, g4.z, g4.w};
  float bb[4] = {b4.x, b4.y, b4.z, b4.w};
  u16 o[4];
  for (int j = 0; j < 4; ++j) o[j] = f2bf((vv[j] - mu) * r * gg[j] + bb[j]);
  ((ushort4*)(out + (size_t)row * 1024 + c))[0] = *(ushort4*)o;
}

// ---------------- GEMM (m97 structure): C = act(A @ Bt^T + bias) (+res) -----
// A[M,K], Bt[N,K] bf16. 128x128 tile, BK=32, 4 waves, 4x4 16x16x32 frags/wave.
// Staging via global_load_lds dwordx4 (wave-uniform LDS dest, linear layout).
template<bool RES_F32, bool GELU>
__global__ __launch_bounds__(256)
void gemm_kernel(const u16* __restrict__ A, const u16* __restrict__ Bt,
                 const float* __restrict__ bias, const float* __restrict__ res,
                 void* __restrict__ Cout, int M, int N, int K) {
  __shared__ u16 As[128][32];
  __shared__ u16 Bs[128][32];
  const int t = threadIdx.x, lane = t & 63, w = t >> 6;
  const int wr = w >> 1, wc = w & 1;
  const int m0 = blockIdx.y * 128, n0 = blockIdx.x * 128;
  const int fr = lane & 15, fg = lane >> 4;
  // staging: wave w, issue i covers tile rows 16*(w+4i)..+15; lane l -> row +l/4, col (l&3)*8
  const int srow = lane >> 2, scol = (lane & 3) * 8;
  const u16* Ag0 = &A[(size_t)(m0 + w * 16 + srow) * K + scol];
  const u16* Ag1 = Ag0 + (size_t)64 * K;
  const u16* Bg0 = &Bt[(size_t)(n0 + w * 16 + srow) * K + scol];
  const u16* Bg1 = Bg0 + (size_t)64 * K;
  u16* Al0 = &As[w * 16][0];      u16* Al1 = &As[w * 16 + 64][0];
  u16* Bl0 = &Bs[w * 16][0];      u16* Bl1 = &Bs[w * 16 + 64][0];
  f32x4 acc[4][4] = {};
  for (int k0 = 0; k0 < K; k0 += 32) {
    g2l16(Ag0 + k0, Al0);
    g2l16(Ag1 + k0, Al1);
    g2l16(Bg0 + k0, Bl0);
    g2l16(Bg1 + k0, Bl1);
    __syncthreads();   // compiler drains vmcnt before barrier -> LDS valid
    bf16x8 af[4], bfr[4];
    for (int m = 0; m < 4; ++m) af[m] = *(bf16x8*)&As[wr * 64 + m * 16 + fr][fg * 8];
    for (int n = 0; n < 4; ++n) bfr[n] = *(bf16x8*)&Bs[wc * 64 + n * 16 + fr][fg * 8];
    for (int m = 0; m < 4; ++m)
      for (int n = 0; n < 4; ++n)
        acc[m][n] = __builtin_amdgcn_mfma_f32_16x16x32_bf16(af[m], bfr[n], acc[m][n], 0, 0, 0);
    __syncthreads();   // all reads done before next stage overwrites
  }
  for (int m = 0; m < 4; ++m)
    for (int n = 0; n < 4; ++n) {
      const int col = n0 + wc * 64 + n * 16 + fr;
      const float bv = bias ? bias[col] : 0.0f;
      for (int i = 0; i < 4; ++i) {
        const int row = m0 + wr * 64 + m * 16 + fg * 4 + i;
        float v = acc[m][n][i] + bv;
        if (GELU) v = 0.5f * v * (1.0f + erff(v * 0.70710678118654752f));
        if (RES_F32)
          ((float*)Cout)[(size_t)row * N + col] = res[(size_t)row * N + col] + v;
        else
          ((u16*)Cout)[(size_t)row * N + col] = f2bf(v);
      }
    }
}

// ---------------- Flash attention: per-head Dk=64, strided Q/K/V ------------
// grid (T/64, B*H), 256 thr (4 waves x 16 q-rows). 32-key tiles, online softmax.
template<bool CAUSAL>
__global__ __launch_bounds__(256)
void attn_kernel(const u16* __restrict__ Q, int ldq,
                 const u16* __restrict__ K, int ldk,
                 const u16* __restrict__ V, int ldv,
                 u16* __restrict__ O) {
  __shared__ u16 Vs[32][64];
  __shared__ u16 Ps[4][16][32];
  const int bh = blockIdx.y, b = bh >> 4, h = bh & 15;
  const int q0 = blockIdx.x * 64;
  const int w = threadIdx.x >> 6, lane = threadIdx.x & 63;
  const int fr = lane & 15, fg = lane >> 4;
  const int qr = q0 + w * 16;
  const int hcol = h * 64;
  const size_t qrow = (size_t)(b * 1024 + qr + fr);
  bf16x8 qf[2];
  qf[0] = *(const bf16x8*)&Q[qrow * ldq + hcol + fg * 8];
  qf[1] = *(const bf16x8*)&Q[qrow * ldq + hcol + 32 + fg * 8];
  f32x4 o[4] = {};
  float mrow[4], lrow[4] = {};
  for (int i = 0; i < 4; ++i) mrow[i] = -1e30f;
  const int nkt = CAUSAL ? (q0 / 32 + 2) : 32;
  for (int kt = 0; kt < nkt; ++kt) {
    const int k0 = kt * 32;
    {
      const int vr = threadIdx.x >> 3, vc = (threadIdx.x & 7) * 8;
      *(bf16x8*)&Vs[vr][vc] =
          *(const bf16x8*)&V[(size_t)(b * 1024 + k0 + vr) * ldv + hcol + vc];
    }
    __syncthreads();
    f32x4 s0 = {}, s1 = {};
    for (int kk = 0; kk < 2; ++kk) {
      const bf16x8 kf0 = *(const bf16x8*)&K[(size_t)(b * 1024 + k0 + fr) * ldk + hcol + kk * 32 + fg * 8];
      const bf16x8 kf1 = *(const bf16x8*)&K[(size_t)(b * 1024 + k0 + 16 + fr) * ldk + hcol + kk * 32 + fg * 8];
      s0 = __builtin_amdgcn_mfma_f32_16x16x32_bf16(qf[kk], kf0, s0, 0, 0, 0);
      s1 = __builtin_amdgcn_mfma_f32_16x16x32_bf16(qf[kk], kf1, s1, 0, 0, 0);
    }
    float p0[4], p1[4], rm[4];
    for (int i = 0; i < 4; ++i) {
      float a = s0[i] * 0.125f, c = s1[i] * 0.125f;
      if (CAUSAL) {
        const int myq = qr + fg * 4 + i;
        if (k0 + fr > myq) a = -1e30f;
        if (k0 + 16 + fr > myq) c = -1e30f;
      }
      p0[i] = a; p1[i] = c;
      rm[i] = fmaxf(a, c);
    }
    for (int off = 1; off < 16; off <<= 1)
      for (int i = 0; i < 4; ++i) rm[i] = fmaxf(rm[i], __shfl_xor(rm[i], off));
    float rs[4];
    for (int i = 0; i < 4; ++i) {
      const float mn = fmaxf(mrow[i], rm[i]);
      const float sc = __expf(mrow[i] - mn);
      p0[i] = __expf(p0[i] - mn);
      p1[i] = __expf(p1[i] - mn);
      mrow[i] = mn;
      lrow[i] *= sc;
      rs[i] = p0[i] + p1[i];
      for (int nb = 0; nb < 4; ++nb) o[nb][i] *= sc;
    }
    for (int off = 1; off < 16; off <<= 1)
      for (int i = 0; i < 4; ++i) rs[i] += __shfl_xor(rs[i], off);
    for (int i = 0; i < 4; ++i) {
      lrow[i] += rs[i];
      Ps[w][fg * 4 + i][fr] = f2bf(p0[i]);
      Ps[w][fg * 4 + i][16 + fr] = f2bf(p1[i]);
    }
    __syncthreads();
    const bf16x8 pa = *(bf16x8*)&Ps[w][fr][fg * 8];
    for (int nb = 0; nb < 4; ++nb) {
      bf16x8 vb;
      for (int j = 0; j < 8; ++j) ((u16*)&vb)[j] = Vs[fg * 8 + j][nb * 16 + fr];
      o[nb] = __builtin_amdgcn_mfma_f32_16x16x32_bf16(pa, vb, o[nb], 0, 0, 0);
    }
    __syncthreads();
  }
  for (int i = 0; i < 4; ++i) {
    const float inv = 1.0f / lrow[i];
    const size_t row = (size_t)(b * 1024 + qr + fg * 4 + i);
    for (int nb = 0; nb < 4; ++nb)
      O[row * 1024 + hcol + nb * 16 + fr] = f2bf(o[nb][i] * inv);
  }
}

// ---------------------------------------------------------------------------
extern "C" void kernel_launch(void* const* d_in, const int* in_sizes, int n_in,
                              void* d_out, int out_size, void* d_ws, size_t ws_size,
                              hipStream_t stream) {
  const float* dec  = (const float*)d_in[0];
  const float* enc  = (const float*)d_in[1];
  const float* sa_g = (const float*)d_in[4];
  const float* sa_b = (const float*)d_in[5];
  const float* sa_wq = (const float*)d_in[6];
  const float* sa_bq = (const float*)d_in[7];
  const float* sa_wk = (const float*)d_in[8];
  const float* sa_wv = (const float*)d_in[9];
  const float* sa_bv = (const float*)d_in[10];
  const float* sa_wo = (const float*)d_in[11];
  const float* sa_bo = (const float*)d_in[12];
  const float* ca_g = (const float*)d_in[13];
  const float* ca_b = (const float*)d_in[14];
  const float* ca_wq = (const float*)d_in[15];
  const float* ca_bq = (const float*)d_in[16];
  const float* ca_wk = (const float*)d_in[17];
  const float* ca_wv = (const float*)d_in[18];
  const float* ca_bv = (const float*)d_in[19];
  const float* ca_wo = (const float*)d_in[20];
  const float* ca_bo = (const float*)d_in[21];
  const float* mlp_g = (const float*)d_in[22];
  const float* mlp_b = (const float*)d_in[23];
  const float* w1 = (const float*)d_in[24];
  const float* b1 = (const float*)d_in[25];
  const float* w2 = (const float*)d_in[26];
  const float* b2 = (const float*)d_in[27];

  const size_t MB = 1024 * 1024;
  if (ws_size < 97 * MB) return;
  char* ws = (char*)d_ws;
  // persistent weights
  u16* WQKV = (u16*)(ws + 0 * MB);           // [3072][1024]
  u16* CQT  = (u16*)(ws + 6 * MB);           // [1024][1024]
  u16* CKV  = (u16*)(ws + 8 * MB);           // [2048][1024]
  u16* WOT  = (u16*)(ws + 12 * MB);
  u16* COT  = (u16*)(ws + 14 * MB);
  float* B3 = (float*)(ws + 16 * MB);        // 3072 f32
  float* B2 = (float*)(ws + 16 * MB + 16384);// 2048 f32
  // activations (aliased across stages)
  u16* XLN  = (u16*)(ws + 17 * MB);          // [4096][1024]
  u16* AO   = (u16*)(ws + 25 * MB);          // [4096][1024]; stage C: W1T
  u16* W1T  = (u16*)(ws + 25 * MB);          // [4096][1024] (stage C)
  u16* ENC  = (u16*)(ws + 33 * MB);          // [4096][1024]; stage C: part of H1
  u16* FB   = (u16*)(ws + 41 * MB);          // [4096][3072] (stage A)
  u16* EF   = (u16*)(ws + 41 * MB);          // [4096][2048] (stage B)
  u16* CQB  = (u16*)(ws + 57 * MB);          // [4096][1024] (stage B)
  u16* H1   = (u16*)(ws + 33 * MB);          // [4096][4096] (stage C, over ENC+FB)
  float* X1 = (float*)(ws + 65 * MB);        // [4096][1024] f32; stage C: W2T
  u16* W2T  = (u16*)(ws + 65 * MB);          // [1024][4096] (stage C)
  float* X2 = (float*)(ws + 81 * MB);        // [4096][1024] f32
  float* OUT = (float*)d_out;

  const dim3 blk(256);
  // ---- weight prep (stage A/B weights) ----
  transcvt_kernel<<<dim3(32, 32), blk, 0, stream>>>(sa_wq, WQKV, 1024, 1024);
  transcvt_kernel<<<dim3(32, 32), blk, 0, stream>>>(sa_wk, WQKV + 1024 * 1024, 1024, 1024);
  transcvt_kernel<<<dim3(32, 32), blk, 0, stream>>>(sa_wv, WQKV + 2048 * 1024, 1024, 1024);
  transcvt_kernel<<<dim3(32, 32), blk, 0, stream>>>(sa_wo, WOT, 1024, 1024);
  transcvt_kernel<<<dim3(32, 32), blk, 0, stream>>>(ca_wq, CQT, 1024, 1024);
  transcvt_kernel<<<dim3(32, 32), blk, 0, stream>>>(ca_wk, CKV, 1024, 1024);
  transcvt_kernel<<<dim3(32, 32), blk, 0, stream>>>(ca_wv, CKV + 1024 * 1024, 1024, 1024);
  transcvt_kernel<<<dim3(32, 32), blk, 0, stream>>>(ca_wo, COT, 1024, 1024);
  pack_bias3_kernel<<<dim3(12), blk, 0, stream>>>(sa_bq, sa_bv, B3);
  pack_bias2_kernel<<<dim3(8), blk, 0, stream>>>(ca_bv, B2);
  cvt_kernel<<<dim3(4096), blk, 0, stream>>>(enc, ENC);

  // ---- self-attention block ----
  ln_kernel<<<dim3(4096), blk, 0, stream>>>(dec, sa_g, sa_b, XLN);
  gemm_kernel<false, false><<<dim3(24, 32), blk, 0, stream>>>(XLN, WQKV, B3, nullptr, FB, 4096, 3072, 1024);
  attn_kernel<true><<<dim3(16, 64), blk, 0, stream>>>(FB, 3072, FB + 1024, 3072, FB + 2048, 3072, AO);
  gemm_kernel<true, false><<<dim3(8, 32), blk, 0, stream>>>(AO, WOT, sa_bo, dec, X1, 4096, 1024, 1024);

  // ---- cross-attention block ----
  ln_kernel<<<dim3(4096), blk, 0, stream>>>(X1, ca_g, ca_b, XLN);
  gemm_kernel<false, false><<<dim3(16, 32), blk, 0, stream>>>(ENC, CKV, B2, nullptr, EF, 4096, 2048, 1024);
  gemm_kernel<false, false><<<dim3(8, 32), blk, 0, stream>>>(XLN, CQT, ca_bq, nullptr, CQB, 4096, 1024, 1024);
  attn_kernel<false><<<dim3(16, 64), blk, 0, stream>>>(CQB, 1024, EF, 2048, EF + 1024, 2048, AO);
  gemm_kernel<true, false><<<dim3(8, 32), blk, 0, stream>>>(AO, COT, ca_bo, X1, X2, 4096, 1024, 1024);

  // ---- FFN block (W1T/W2T built into freed regions) ----
  transcvt_kernel<<<dim3(128, 32), blk, 0, stream>>>(w1, W1T, 1024, 4096);
  transcvt_kernel<<<dim3(32, 128), blk, 0, stream>>>(w2, W2T, 4096, 1024);
  ln_kernel<<<dim3(4096), blk, 0, stream>>>(X2, mlp_g, mlp_b, XLN);
  gemm_kernel<false, true><<<dim3(32, 32), blk, 0, stream>>>(XLN, W1T, b1, nullptr, H1, 4096, 4096, 1024);
  gemm_kernel<true, false><<<dim3(8, 32), blk, 0, stream>>>(H1, W2T, b2, X2, OUT, 4096, 1024, 4096);
}

// Round 3
// 1149.465 us; speedup vs baseline: 1.1087x; 1.0573x over previous
//
#include <hip/hip_runtime.h>
#include <math.h>

typedef unsigned short u16;
typedef unsigned int   u32;
typedef __attribute__((ext_vector_type(8))) short bf16x8;  // 8 bf16 (4 VGPRs)
typedef __attribute__((ext_vector_type(4))) short bf16x4;  // 4 bf16 (2 VGPRs)
typedef __attribute__((ext_vector_type(4))) float f32x4;

__device__ __forceinline__ u16 f2bf(float f) {
  u32 u = __builtin_bit_cast(u32, f);
  u += 0x7fffu + ((u >> 16) & 1u);   // RNE
  return (u16)(u >> 16);
}

// async global->LDS, 16B per lane. LDS dest must be wave-uniform; HW writes
// lane l's 16B at dest + l*16 (linear). Global src is per-lane.
__device__ __forceinline__ void g2l16(const u16* g, u16* l) {
  __builtin_amdgcn_global_load_lds(
      (const __attribute__((address_space(1))) unsigned int*)g,
      (__attribute__((address_space(3))) unsigned int*)l, 16, 0, 0);
}

// ---------------- transpose + convert: W[K][N] f32 -> Wt[N][K] bf16 ----------
__global__ __launch_bounds__(256)
void transcvt_kernel(const float* __restrict__ W, u16* __restrict__ Wt, int K, int N) {
  __shared__ float tile[32][33];
  const int n0 = blockIdx.x * 32, k0 = blockIdx.y * 32;
  const int tx = threadIdx.x & 31, ty = threadIdx.x >> 5;  // 32 x 8
  for (int i = 0; i < 4; ++i)
    tile[ty + 8 * i][tx] = W[(size_t)(k0 + ty + 8 * i) * N + n0 + tx];
  __syncthreads();
  for (int i = 0; i < 4; ++i)
    Wt[(size_t)(n0 + ty + 8 * i) * K + k0 + tx] = f2bf(tile[tx][ty + 8 * i]);
}

// ---------------- elementwise convert f32 -> bf16 ----------------------------
__global__ __launch_bounds__(256)
void cvt_kernel(const float* __restrict__ in, u16* __restrict__ out) {
  const int i = blockIdx.x * 256 + threadIdx.x;
  const float4 v = ((const float4*)in)[i];
  u16 o[4] = {f2bf(v.x), f2bf(v.y), f2bf(v.z), f2bf(v.w)};
  ((ushort4*)out)[i] = *(ushort4*)o;
}

// ---------------- bias packing (B3: [bq|0|bv], B2: [0|bv]) ------------------
__global__ __launch_bounds__(256)
void pack_bias_kernel(const float* __restrict__ bq, const float* __restrict__ bv,
                      const float* __restrict__ cbv,
                      float* __restrict__ B3, float* __restrict__ B2) {
  const int i = blockIdx.x * 256 + threadIdx.x;   // 5120 total
  if (i < 3072) {
    float v = 0.0f;
    if (i < 1024) v = bq[i];
    else if (i >= 2048) v = bv[i - 2048];
    B3[i] = v;
  } else {
    const int j = i - 3072;
    B2[j] = (j >= 1024) ? cbv[j - 1024] : 0.0f;
  }
}

// ---------------- LayerNorm: rows of 1024, f32 in -> bf16 out ---------------
__global__ __launch_bounds__(256)
void ln_kernel(const float* __restrict__ x, const float* __restrict__ g,
               const float* __restrict__ b, u16* __restrict__ out) {
  const int row = blockIdx.x;
  const float4 v4 = ((const float4*)(x + (size_t)row * 1024))[threadIdx.x];
  float vv[4] = {v4.x, v4.y, v4.z, v4.w};
  float s = vv[0] + vv[1] + vv[2] + vv[3];
  float s2 = vv[0] * vv[0] + vv[1] * vv[1] + vv[2] * vv[2] + vv[3] * vv[3];
  for (int m = 1; m < 64; m <<= 1) { s += __shfl_xor(s, m); s2 += __shfl_xor(s2, m); }
  __shared__ float ss[4], ss2[4];
  const int w = threadIdx.x >> 6;
  if ((threadIdx.x & 63) == 0) { ss[w] = s; ss2[w] = s2; }
  __syncthreads();
  s = ss[0] + ss[1] + ss[2] + ss[3];
  s2 = ss2[0] + ss2[1] + ss2[2] + ss2[3];
  const float mu = s * (1.0f / 1024.0f);
  const float var = s2 * (1.0f / 1024.0f) - mu * mu;
  const float r = rsqrtf(var + 1e-5f);
  const int c = threadIdx.x * 4;
  const float4 g4 = ((const float4*)g)[threadIdx.x];
  const float4 b4 = ((const float4*)b)[threadIdx.x];
  float gg[4] = {g4.x, g4.y, g4.z, g4.w};
  float bb[4] = {b4.x, b4.y, b4.z, b4.w};
  u16 o[4];
  for (int j = 0; j < 4; ++j) o[j] = f2bf((vv[j] - mu) * r * gg[j] + bb[j]);
  ((ushort4*)(out + (size_t)row * 1024 + c))[0] = *(ushort4*)o;
}

// ---------------- GEMM: 2-phase double-buffered prefetch --------------------
// C = act(A[M,K] @ Bt[N,K]^T + bias) (+res). 128x128 tile, BK=32, 4 waves.
// STAGE(next) issued BEFORE compute(cur); single barrier per K-step.
template<bool RES_F32, bool GELU>
__global__ __launch_bounds__(256)
void gemm_kernel(const u16* __restrict__ A, const u16* __restrict__ Bt,
                 const float* __restrict__ bias, const float* __restrict__ res,
                 void* __restrict__ Cout, int M, int N, int K) {
  __shared__ u16 As[2][128][32];
  __shared__ u16 Bs[2][128][32];
  const int t = threadIdx.x, lane = t & 63, w = t >> 6;
  const int wr = w >> 1, wc = w & 1;
  const int m0 = blockIdx.y * 128, n0 = blockIdx.x * 128;
  const int fr = lane & 15, fg = lane >> 4;
  const int srow = lane >> 2, scol = (lane & 3) * 8;
  const u16* Ag0 = &A[(size_t)(m0 + w * 16 + srow) * K + scol];
  const u16* Ag1 = Ag0 + (size_t)64 * K;
  const u16* Bg0 = &Bt[(size_t)(n0 + w * 16 + srow) * K + scol];
  const u16* Bg1 = Bg0 + (size_t)64 * K;
  f32x4 acc[4][4] = {};
  // prologue: stage tile 0 into buf 0
  g2l16(Ag0, &As[0][w * 16][0]);
  g2l16(Ag1, &As[0][w * 16 + 64][0]);
  g2l16(Bg0, &Bs[0][w * 16][0]);
  g2l16(Bg1, &Bs[0][w * 16 + 64][0]);
  __syncthreads();
  int cur = 0;
  for (int k0 = 0; k0 < K; k0 += 32) {
    if (k0 + 32 < K) {   // prefetch next tile into other buffer (overlaps MFMA)
      const int nx = cur ^ 1, kn = k0 + 32;
      g2l16(Ag0 + kn, &As[nx][w * 16][0]);
      g2l16(Ag1 + kn, &As[nx][w * 16 + 64][0]);
      g2l16(Bg0 + kn, &Bs[nx][w * 16][0]);
      g2l16(Bg1 + kn, &Bs[nx][w * 16 + 64][0]);
    }
    bf16x8 af[4], bfr[4];
    for (int m = 0; m < 4; ++m) af[m] = *(bf16x8*)&As[cur][wr * 64 + m * 16 + fr][fg * 8];
    for (int n = 0; n < 4; ++n) bfr[n] = *(bf16x8*)&Bs[cur][wc * 64 + n * 16 + fr][fg * 8];
    __builtin_amdgcn_s_setprio(1);
    for (int m = 0; m < 4; ++m)
      for (int n = 0; n < 4; ++n)
        acc[m][n] = __builtin_amdgcn_mfma_f32_16x16x32_bf16(af[m], bfr[n], acc[m][n], 0, 0, 0);
    __builtin_amdgcn_s_setprio(0);
    __syncthreads();   // drains vmcnt (next tile staged) + lgkm (reads done)
    cur ^= 1;
  }
  for (int m = 0; m < 4; ++m)
    for (int n = 0; n < 4; ++n) {
      const int col = n0 + wc * 64 + n * 16 + fr;
      const float bv = bias ? bias[col] : 0.0f;
      for (int i = 0; i < 4; ++i) {
        const int row = m0 + wr * 64 + m * 16 + fg * 4 + i;
        float v = acc[m][n][i] + bv;
        if (GELU) v = 0.5f * v * (1.0f + erff(v * 0.70710678118654752f));
        if (RES_F32)
          ((float*)Cout)[(size_t)row * N + col] = res[(size_t)row * N + col] + v;
        else
          ((u16*)Cout)[(size_t)row * N + col] = f2bf(v);
      }
    }
}

// ---------------- Flash attention: per-head Dk=64, strided Q/K/V ------------
// grid (T/64, B*H), 256 thr (4 waves x 16 q-rows). 32-key tiles, online softmax.
// V stored TRANSPOSED in LDS (VsT[64][36]) -> PV fragment = 2x ds_read_b64.
// Ps rows padded to 40 u16 (80B, 16B-aligned) -> single ds_read_b128.
template<bool CAUSAL>
__global__ __launch_bounds__(256)
void attn_kernel(const u16* __restrict__ Q, int ldq,
                 const u16* __restrict__ K, int ldk,
                 const u16* __restrict__ V, int ldv,
                 u16* __restrict__ O) {
  __shared__ u16 VsT[64][36];
  __shared__ u16 Ps[4][16][40];
  const int bh = blockIdx.y, b = bh >> 4, h = bh & 15;
  const int q0 = blockIdx.x * 64;
  const int t = threadIdx.x;
  const int w = t >> 6, lane = t & 63;
  const int fr = lane & 15, fg = lane >> 4;
  const int qr = q0 + w * 16;
  const int hcol = h * 64;
  const size_t qrow = (size_t)(b * 1024 + qr + fr);
  bf16x8 qf[2];
  qf[0] = *(const bf16x8*)&Q[qrow * ldq + hcol + fg * 8];
  qf[1] = *(const bf16x8*)&Q[qrow * ldq + hcol + 32 + fg * 8];
  f32x4 o[4] = {};
  float mrow[4], lrow[4] = {};
  for (int i = 0; i < 4; ++i) mrow[i] = -1e30f;
  const int vr = t >> 3, vc = (t & 7) * 8;
  const int nkt = CAUSAL ? (q0 / 32 + 2) : 32;
  for (int kt = 0; kt < nkt; ++kt) {
    const int k0 = kt * 32;
    {  // stage V transposed: thread covers row k0+vr, cols vc..vc+7
      const bf16x8 vv = *(const bf16x8*)&V[(size_t)(b * 1024 + k0 + vr) * ldv + hcol + vc];
      #pragma unroll
      for (int j = 0; j < 8; ++j) VsT[vc + j][vr] = ((const u16*)&vv)[j];
    }
    __syncthreads();
    f32x4 s0 = {}, s1 = {};
    {
      const bf16x8 k00 = *(const bf16x8*)&K[(size_t)(b * 1024 + k0 + fr) * ldk + hcol + fg * 8];
      const bf16x8 k01 = *(const bf16x8*)&K[(size_t)(b * 1024 + k0 + fr) * ldk + hcol + 32 + fg * 8];
      const bf16x8 k10 = *(const bf16x8*)&K[(size_t)(b * 1024 + k0 + 16 + fr) * ldk + hcol + fg * 8];
      const bf16x8 k11 = *(const bf16x8*)&K[(size_t)(b * 1024 + k0 + 16 + fr) * ldk + hcol + 32 + fg * 8];
      __builtin_amdgcn_s_setprio(1);
      s0 = __builtin_amdgcn_mfma_f32_16x16x32_bf16(qf[0], k00, s0, 0, 0, 0);
      s1 = __builtin_amdgcn_mfma_f32_16x16x32_bf16(qf[0], k10, s1, 0, 0, 0);
      s0 = __builtin_amdgcn_mfma_f32_16x16x32_bf16(qf[1], k01, s0, 0, 0, 0);
      s1 = __builtin_amdgcn_mfma_f32_16x16x32_bf16(qf[1], k11, s1, 0, 0, 0);
      __builtin_amdgcn_s_setprio(0);
    }
    float p0[4], p1[4], rm[4];
    for (int i = 0; i < 4; ++i) {
      float a = s0[i] * 0.125f, c = s1[i] * 0.125f;
      if (CAUSAL) {
        const int myq = qr + fg * 4 + i;
        if (k0 + fr > myq) a = -1e30f;
        if (k0 + 16 + fr > myq) c = -1e30f;
      }
      p0[i] = a; p1[i] = c;
      rm[i] = fmaxf(a, c);
    }
    for (int off = 1; off < 16; off <<= 1)
      for (int i = 0; i < 4; ++i) rm[i] = fmaxf(rm[i], __shfl_xor(rm[i], off));
    float rs[4];
    for (int i = 0; i < 4; ++i) {
      const float mn = fmaxf(mrow[i], rm[i]);
      const float sc = __expf(mrow[i] - mn);
      p0[i] = __expf(p0[i] - mn);
      p1[i] = __expf(p1[i] - mn);
      mrow[i] = mn;
      lrow[i] *= sc;
      rs[i] = p0[i] + p1[i];
      for (int nb = 0; nb < 4; ++nb) o[nb][i] *= sc;
    }
    for (int off = 1; off < 16; off <<= 1)
      for (int i = 0; i < 4; ++i) rs[i] += __shfl_xor(rs[i], off);
    for (int i = 0; i < 4; ++i) {
      lrow[i] += rs[i];
      Ps[w][fg * 4 + i][fr] = f2bf(p0[i]);
      Ps[w][fg * 4 + i][16 + fr] = f2bf(p1[i]);
    }
    __syncthreads();
    const bf16x8 pa = *(bf16x8*)&Ps[w][fr][fg * 8];
    __builtin_amdgcn_s_setprio(1);
    #pragma unroll
    for (int nb = 0; nb < 4; ++nb) {
      const bf16x4 v0 = *(const bf16x4*)&VsT[nb * 16 + fr][fg * 8];
      const bf16x4 v1 = *(const bf16x4*)&VsT[nb * 16 + fr][fg * 8 + 4];
      bf16x8 vb;
      #pragma unroll
      for (int j = 0; j < 4; ++j) { vb[j] = v0[j]; vb[j + 4] = v1[j]; }
      o[nb] = __builtin_amdgcn_mfma_f32_16x16x32_bf16(pa, vb, o[nb], 0, 0, 0);
    }
    __builtin_amdgcn_s_setprio(0);
    __syncthreads();
  }
  for (int i = 0; i < 4; ++i) {
    const float inv = 1.0f / lrow[i];
    const size_t row = (size_t)(b * 1024 + qr + fg * 4 + i);
    for (int nb = 0; nb < 4; ++nb)
      O[row * 1024 + hcol + nb * 16 + fr] = f2bf(o[nb][i] * inv);
  }
}

// ---------------------------------------------------------------------------
extern "C" void kernel_launch(void* const* d_in, const int* in_sizes, int n_in,
                              void* d_out, int out_size, void* d_ws, size_t ws_size,
                              hipStream_t stream) {
  const float* dec  = (const float*)d_in[0];
  const float* enc  = (const float*)d_in[1];
  const float* sa_g = (const float*)d_in[4];
  const float* sa_b = (const float*)d_in[5];
  const float* sa_wq = (const float*)d_in[6];
  const float* sa_bq = (const float*)d_in[7];
  const float* sa_wk = (const float*)d_in[8];
  const float* sa_wv = (const float*)d_in[9];
  const float* sa_bv = (const float*)d_in[10];
  const float* sa_wo = (const float*)d_in[11];
  const float* sa_bo = (const float*)d_in[12];
  const float* ca_g = (const float*)d_in[13];
  const float* ca_b = (const float*)d_in[14];
  const float* ca_wq = (const float*)d_in[15];
  const float* ca_bq = (const float*)d_in[16];
  const float* ca_wk = (const float*)d_in[17];
  const float* ca_wv = (const float*)d_in[18];
  const float* ca_bv = (const float*)d_in[19];
  const float* ca_wo = (const float*)d_in[20];
  const float* ca_bo = (const float*)d_in[21];
  const float* mlp_g = (const float*)d_in[22];
  const float* mlp_b = (const float*)d_in[23];
  const float* w1 = (const float*)d_in[24];
  const float* b1 = (const float*)d_in[25];
  const float* w2 = (const float*)d_in[26];
  const float* b2 = (const float*)d_in[27];

  const size_t MB = 1024 * 1024;
  if (ws_size < 97 * MB) return;
  char* ws = (char*)d_ws;
  // persistent weights
  u16* WQKV = (u16*)(ws + 0 * MB);           // [3072][1024]
  u16* CQT  = (u16*)(ws + 6 * MB);           // [1024][1024]
  u16* CKV  = (u16*)(ws + 8 * MB);           // [2048][1024]
  u16* WOT  = (u16*)(ws + 12 * MB);
  u16* COT  = (u16*)(ws + 14 * MB);
  float* B3 = (float*)(ws + 16 * MB);        // 3072 f32
  float* B2 = (float*)(ws + 16 * MB + 16384);// 2048 f32
  // activations (aliased across stages)
  u16* XLN  = (u16*)(ws + 17 * MB);          // [4096][1024]
  u16* AO   = (u16*)(ws + 25 * MB);          // [4096][1024]; stage C: W1T
  u16* W1T  = (u16*)(ws + 25 * MB);          // [4096][1024] (stage C)
  u16* ENC  = (u16*)(ws + 33 * MB);          // [4096][1024]; stage C: part of H1
  u16* FB   = (u16*)(ws + 41 * MB);          // [4096][3072] (stage A)
  u16* EF   = (u16*)(ws + 41 * MB);          // [4096][2048] (stage B)
  u16* CQB  = (u16*)(ws + 57 * MB);          // [4096][1024] (stage B)
  u16* H1   = (u16*)(ws + 33 * MB);          // [4096][4096] (stage C, over ENC+FB)
  float* X1 = (float*)(ws + 65 * MB);        // [4096][1024] f32; stage C: W2T
  u16* W2T  = (u16*)(ws + 65 * MB);          // [1024][4096] (stage C)
  float* X2 = (float*)(ws + 81 * MB);        // [4096][1024] f32
  float* OUT = (float*)d_out;

  const dim3 blk(256);
  // ---- weight prep ----
  transcvt_kernel<<<dim3(32, 32), blk, 0, stream>>>(sa_wq, WQKV, 1024, 1024);
  transcvt_kernel<<<dim3(32, 32), blk, 0, stream>>>(sa_wk, WQKV + 1024 * 1024, 1024, 1024);
  transcvt_kernel<<<dim3(32, 32), blk, 0, stream>>>(sa_wv, WQKV + 2048 * 1024, 1024, 1024);
  transcvt_kernel<<<dim3(32, 32), blk, 0, stream>>>(sa_wo, WOT, 1024, 1024);
  transcvt_kernel<<<dim3(32, 32), blk, 0, stream>>>(ca_wq, CQT, 1024, 1024);
  transcvt_kernel<<<dim3(32, 32), blk, 0, stream>>>(ca_wk, CKV, 1024, 1024);
  transcvt_kernel<<<dim3(32, 32), blk, 0, stream>>>(ca_wv, CKV + 1024 * 1024, 1024, 1024);
  transcvt_kernel<<<dim3(32, 32), blk, 0, stream>>>(ca_wo, COT, 1024, 1024);
  pack_bias_kernel<<<dim3(20), blk, 0, stream>>>(sa_bq, sa_bv, ca_bv, B3, B2);
  cvt_kernel<<<dim3(4096), blk, 0, stream>>>(enc, ENC);

  // ---- self-attention block ----
  ln_kernel<<<dim3(4096), blk, 0, stream>>>(dec, sa_g, sa_b, XLN);
  gemm_kernel<false, false><<<dim3(24, 32), blk, 0, stream>>>(XLN, WQKV, B3, nullptr, FB, 4096, 3072, 1024);
  attn_kernel<true><<<dim3(16, 64), blk, 0, stream>>>(FB, 3072, FB + 1024, 3072, FB + 2048, 3072, AO);
  gemm_kernel<true, false><<<dim3(8, 32), blk, 0, stream>>>(AO, WOT, sa_bo, dec, X1, 4096, 1024, 1024);

  // ---- cross-attention block ----
  ln_kernel<<<dim3(4096), blk, 0, stream>>>(X1, ca_g, ca_b, XLN);
  gemm_kernel<false, false><<<dim3(16, 32), blk, 0, stream>>>(ENC, CKV, B2, nullptr, EF, 4096, 2048, 1024);
  gemm_kernel<false, false><<<dim3(8, 32), blk, 0, stream>>>(XLN, CQT, ca_bq, nullptr, CQB, 4096, 1024, 1024);
  attn_kernel<false><<<dim3(16, 64), blk, 0, stream>>>(CQB, 1024, EF, 2048, EF + 1024, 2048, AO);
  gemm_kernel<true, false><<<dim3(8, 32), blk, 0, stream>>>(AO, COT, ca_bo, X1, X2, 4096, 1024, 1024);

  // ---- FFN block ----
  transcvt_kernel<<<dim3(128, 32), blk, 0, stream>>>(w1, W1T, 1024, 4096);
  transcvt_kernel<<<dim3(32, 128), blk, 0, stream>>>(w2, W2T, 4096, 1024);
  ln_kernel<<<dim3(4096), blk, 0, stream>>>(X2, mlp_g, mlp_b, XLN);
  gemm_kernel<false, true><<<dim3(32, 32), blk, 0, stream>>>(XLN, W1T, b1, nullptr, H1, 4096, 4096, 1024);
  gemm_kernel<true, false><<<dim3(8, 32), blk, 0, stream>>>(H1, W2T, b2, X2, OUT, 4096, 1024, 4096);
}

// Round 4
// 455.870 us; speedup vs baseline: 2.7956x; 2.5215x over previous
//
#include <hip/hip_runtime.h>
#include <math.h>

typedef unsigned short u16;
typedef unsigned int   u32;
typedef __attribute__((ext_vector_type(8))) short bf16x8;  // 8 bf16 (4 VGPRs)
typedef __attribute__((ext_vector_type(4))) float f32x4;

__device__ __forceinline__ u16 f2bf(float f) {
  u32 u = __builtin_bit_cast(u32, f);
  u += 0x7fffu + ((u >> 16) & 1u);   // RNE
  return (u16)(u >> 16);
}

// async global->LDS, 16B per lane. LDS dest must be wave-uniform; HW writes
// lane l's 16B at dest + l*16 (linear). Global src is per-lane.
__device__ __forceinline__ void g2l16(const u16* g, u16* l) {
  __builtin_amdgcn_global_load_lds(
      (const __attribute__((address_space(1))) unsigned int*)g,
      (__attribute__((address_space(3))) unsigned int*)l, 16, 0, 0);
}

// ---------------- batched transpose+convert for 8x [1024][1024] weights ------
struct TC8 { const float* s[8]; u16* d[8]; };
__global__ __launch_bounds__(256)
void transcvt8_kernel(TC8 p) {
  const float* __restrict__ W = p.s[blockIdx.z];
  u16* __restrict__ Wt = p.d[blockIdx.z];
  __shared__ float tile[32][33];
  const int n0 = blockIdx.x * 32, k0 = blockIdx.y * 32;
  const int tx = threadIdx.x & 31, ty = threadIdx.x >> 5;  // 32 x 8
  for (int i = 0; i < 4; ++i)
    tile[ty + 8 * i][tx] = W[(size_t)(k0 + ty + 8 * i) * 1024 + n0 + tx];
  __syncthreads();
  for (int i = 0; i < 4; ++i)
    Wt[(size_t)(n0 + ty + 8 * i) * 1024 + k0 + tx] = f2bf(tile[tx][ty + 8 * i]);
}

// ---------------- transpose + convert: W[K][N] f32 -> Wt[N][K] bf16 ----------
__global__ __launch_bounds__(256)
void transcvt_kernel(const float* __restrict__ W, u16* __restrict__ Wt, int K, int N) {
  __shared__ float tile[32][33];
  const int n0 = blockIdx.x * 32, k0 = blockIdx.y * 32;
  const int tx = threadIdx.x & 31, ty = threadIdx.x >> 5;
  for (int i = 0; i < 4; ++i)
    tile[ty + 8 * i][tx] = W[(size_t)(k0 + ty + 8 * i) * N + n0 + tx];
  __syncthreads();
  for (int i = 0; i < 4; ++i)
    Wt[(size_t)(n0 + ty + 8 * i) * K + k0 + tx] = f2bf(tile[tx][ty + 8 * i]);
}

// ---------------- elementwise convert f32 -> bf16 ----------------------------
__global__ __launch_bounds__(256)
void cvt_kernel(const float* __restrict__ in, u16* __restrict__ out) {
  const int i = blockIdx.x * 256 + threadIdx.x;
  const float4 v = ((const float4*)in)[i];
  u16 o[4] = {f2bf(v.x), f2bf(v.y), f2bf(v.z), f2bf(v.w)};
  ((ushort4*)out)[i] = *(ushort4*)o;
}

// ---------------- bias packing (B3: [bq|0|bv], B2: [0|bv]) ------------------
__global__ __launch_bounds__(256)
void pack_bias_kernel(const float* __restrict__ bq, const float* __restrict__ bv,
                      const float* __restrict__ cbv,
                      float* __restrict__ B3, float* __restrict__ B2) {
  const int i = blockIdx.x * 256 + threadIdx.x;   // 5120 total
  if (i < 3072) {
    float v = 0.0f;
    if (i < 1024) v = bq[i];
    else if (i >= 2048) v = bv[i - 2048];
    B3[i] = v;
  } else {
    const int j = i - 3072;
    B2[j] = (j >= 1024) ? cbv[j - 1024] : 0.0f;
  }
}

// ---------------- LayerNorm: rows of 1024, f32 in -> bf16 out ---------------
__global__ __launch_bounds__(256)
void ln_kernel(const float* __restrict__ x, const float* __restrict__ g,
               const float* __restrict__ b, u16* __restrict__ out) {
  const int row = blockIdx.x;
  const float4 v4 = ((const float4*)(x + (size_t)row * 1024))[threadIdx.x];
  float vv[4] = {v4.x, v4.y, v4.z, v4.w};
  float s = vv[0] + vv[1] + vv[2] + vv[3];
  float s2 = vv[0] * vv[0] + vv[1] * vv[1] + vv[2] * vv[2] + vv[3] * vv[3];
  for (int m = 1; m < 64; m <<= 1) { s += __shfl_xor(s, m); s2 += __shfl_xor(s2, m); }
  __shared__ float ss[4], ss2[4];
  const int w = threadIdx.x >> 6;
  if ((threadIdx.x & 63) == 0) { ss[w] = s; ss2[w] = s2; }
  __syncthreads();
  s = ss[0] + ss[1] + ss[2] + ss[3];
  s2 = ss2[0] + ss2[1] + ss2[2] + ss2[3];
  const float mu = s * (1.0f / 1024.0f);
  const float var = s2 * (1.0f / 1024.0f) - mu * mu;
  const float r = rsqrtf(var + 1e-5f);
  const int c = threadIdx.x * 4;
  const float4 g4 = ((const float4*)g)[threadIdx.x];
  const float4 b4 = ((const float4*)b)[threadIdx.x];
  float gg[4] = {g4.x, g4.y, g4.z, g4.w};
  float bb[4] = {b4.x, b4.y, b4.z, b4.w};
  u16 o[4];
  for (int j = 0; j < 4; ++j) o[j] = f2bf((vv[j] - mu) * r * gg[j] + bb[j]);
  ((ushort4*)(out + (size_t)row * 1024 + c))[0] = *(ushort4*)o;
}

// ---------------- GEMM: 128x128 tile, 8 waves (512 thr), 2-phase dbuf -------
// C = act(A[M,K] @ Bt[N,K]^T + bias) (+res). Wave grid 2x4; wave = 64x32 out.
// XCD-aware block swizzle (requires nwg % 8 == 0, all our grids satisfy).
template<bool RES_F32, bool GELU>
__global__ __launch_bounds__(512)
void gemm_kernel(const u16* __restrict__ A, const u16* __restrict__ Bt,
                 const float* __restrict__ bias, const float* __restrict__ res,
                 void* __restrict__ Cout, int M, int N, int K) {
  __shared__ u16 As[2][128][32];
  __shared__ u16 Bs[2][128][32];
  const int t = threadIdx.x, lane = t & 63, w = t >> 6;
  const int wr = w >> 2, wc = w & 3;
  // XCD swizzle: consecutive flat ids round-robin XCDs; remap so each XCD
  // gets a contiguous logical range (shared A-panels stay in one XCD L2).
  const int nwg = gridDim.x * gridDim.y;
  int bid = blockIdx.y * gridDim.x + blockIdx.x;
  bid = (bid & 7) * (nwg >> 3) + (bid >> 3);
  const int m0 = (bid / gridDim.x) * 128, n0 = (bid % gridDim.x) * 128;
  const int fr = lane & 15, fg = lane >> 4;
  const int srow = lane >> 2, scol = (lane & 3) * 8;
  const u16* Ag = &A[(size_t)(m0 + w * 16 + srow) * K + scol];
  const u16* Bg = &Bt[(size_t)(n0 + w * 16 + srow) * K + scol];
  f32x4 acc[4][2] = {};
  g2l16(Ag, &As[0][w * 16][0]);
  g2l16(Bg, &Bs[0][w * 16][0]);
  __syncthreads();
  int cur = 0;
  for (int k0 = 0; k0 < K; k0 += 32) {
    if (k0 + 32 < K) {   // prefetch next tile (overlaps with MFMA below)
      const int nx = cur ^ 1, kn = k0 + 32;
      g2l16(Ag + kn, &As[nx][w * 16][0]);
      g2l16(Bg + kn, &Bs[nx][w * 16][0]);
    }
    bf16x8 af[4], bfr[2];
    for (int m = 0; m < 4; ++m) af[m] = *(bf16x8*)&As[cur][wr * 64 + m * 16 + fr][fg * 8];
    for (int n = 0; n < 2; ++n) bfr[n] = *(bf16x8*)&Bs[cur][wc * 32 + n * 16 + fr][fg * 8];
    __builtin_amdgcn_s_setprio(1);
    for (int m = 0; m < 4; ++m)
      for (int n = 0; n < 2; ++n)
        acc[m][n] = __builtin_amdgcn_mfma_f32_16x16x32_bf16(af[m], bfr[n], acc[m][n], 0, 0, 0);
    __builtin_amdgcn_s_setprio(0);
    __syncthreads();
    cur ^= 1;
  }
  for (int m = 0; m < 4; ++m)
    for (int n = 0; n < 2; ++n) {
      const int col = n0 + wc * 32 + n * 16 + fr;
      const float bv = bias ? bias[col] : 0.0f;
      for (int i = 0; i < 4; ++i) {
        const int row = m0 + wr * 64 + m * 16 + fg * 4 + i;
        float v = acc[m][n][i] + bv;
        if (GELU) v = 0.5f * v * (1.0f + erff(v * 0.70710678118654752f));
        if (RES_F32)
          ((float*)Cout)[(size_t)row * N + col] = res[(size_t)row * N + col] + v;
        else
          ((u16*)Cout)[(size_t)row * N + col] = f2bf(v);
      }
    }
}

// ---------------- Flash attention: per-head Dk=64, KVBLK=64 -----------------
// grid (T/64, B*H), 256 thr (4 waves x 16 q-rows). 64-key tiles, online softmax.
// V transposed in LDS (VsT[64 dims][72]); Ps rows padded to 72 (144B, 16B-align).
template<bool CAUSAL>
__global__ __launch_bounds__(256)
void attn_kernel(const u16* __restrict__ Q, int ldq,
                 const u16* __restrict__ K, int ldk,
                 const u16* __restrict__ V, int ldv,
                 u16* __restrict__ O) {
  __shared__ u16 VsT[64][72];
  __shared__ u16 Ps[4][16][72];
  const int bh = blockIdx.y, b = bh >> 4, h = bh & 15;
  const int q0 = blockIdx.x * 64;
  const int t = threadIdx.x;
  const int w = t >> 6, lane = t & 63;
  const int fr = lane & 15, fg = lane >> 4;
  const int qr = q0 + w * 16;
  const int hcol = h * 64;
  const size_t qrow = (size_t)(b * 1024 + qr + fr);
  bf16x8 qf[2];
  qf[0] = *(const bf16x8*)&Q[qrow * ldq + hcol + fg * 8];
  qf[1] = *(const bf16x8*)&Q[qrow * ldq + hcol + 32 + fg * 8];
  f32x4 o[4] = {};
  float mrow[4], lrow[4] = {};
  for (int i = 0; i < 4; ++i) mrow[i] = -1e30f;
  // V staging coords: thread covers keys {2p, 2p+1} x dims [c8, c8+8)
  const int vp = t >> 3, vc8 = (t & 7) * 8;
  const int nkt = CAUSAL ? (blockIdx.x + 1) : 16;
  for (int kt = 0; kt < nkt; ++kt) {
    const int k0 = kt * 64;
    {  // stage V transposed, paired b32 writes
      const bf16x8 va = *(const bf16x8*)&V[(size_t)(b * 1024 + k0 + 2 * vp) * ldv + hcol + vc8];
      const bf16x8 vb = *(const bf16x8*)&V[(size_t)(b * 1024 + k0 + 2 * vp + 1) * ldv + hcol + vc8];
      #pragma unroll
      for (int j = 0; j < 8; ++j) {
        u16 pair[2] = {((const u16*)&va)[j], ((const u16*)&vb)[j]};
        *(u32*)&VsT[vc8 + j][2 * vp] = *(u32*)pair;
      }
    }
    __syncthreads();
    f32x4 s[4] = {};
    {
      #pragma unroll
      for (int kk = 0; kk < 2; ++kk) {
        bf16x8 kf[4];
        #pragma unroll
        for (int j = 0; j < 4; ++j)
          kf[j] = *(const bf16x8*)&K[(size_t)(b * 1024 + k0 + j * 16 + fr) * ldk + hcol + kk * 32 + fg * 8];
        __builtin_amdgcn_s_setprio(1);
        #pragma unroll
        for (int j = 0; j < 4; ++j)
          s[j] = __builtin_amdgcn_mfma_f32_16x16x32_bf16(qf[kk], kf[j], s[j], 0, 0, 0);
        __builtin_amdgcn_s_setprio(0);
      }
    }
    float p[4][4], rm[4];
    const bool domask = CAUSAL && (kt == nkt - 1);
    for (int i = 0; i < 4; ++i) rm[i] = -1e30f;
    #pragma unroll
    for (int j = 0; j < 4; ++j)
      for (int i = 0; i < 4; ++i) {
        float a = s[j][i] * 0.125f;
        if (domask) {
          const int myq = qr + fg * 4 + i;
          if (k0 + j * 16 + fr > myq) a = -1e30f;
        }
        p[j][i] = a;
        rm[i] = fmaxf(rm[i], a);
      }
    for (int off = 1; off < 16; off <<= 1)
      for (int i = 0; i < 4; ++i) rm[i] = fmaxf(rm[i], __shfl_xor(rm[i], off));
    float rs[4];
    for (int i = 0; i < 4; ++i) {
      const float mn = fmaxf(mrow[i], rm[i]);
      const float sc = __expf(mrow[i] - mn);
      float acc = 0.0f;
      #pragma unroll
      for (int j = 0; j < 4; ++j) { p[j][i] = __expf(p[j][i] - mn); acc += p[j][i]; }
      mrow[i] = mn;
      lrow[i] *= sc;
      rs[i] = acc;
      for (int nb = 0; nb < 4; ++nb) o[nb][i] *= sc;
    }
    for (int off = 1; off < 16; off <<= 1)
      for (int i = 0; i < 4; ++i) rs[i] += __shfl_xor(rs[i], off);
    for (int i = 0; i < 4; ++i) {
      lrow[i] += rs[i];
      #pragma unroll
      for (int j = 0; j < 4; ++j) Ps[w][fg * 4 + i][j * 16 + fr] = f2bf(p[j][i]);
    }
    __syncthreads();
    {
      const bf16x8 pa0 = *(bf16x8*)&Ps[w][fr][fg * 8];
      const bf16x8 pa1 = *(bf16x8*)&Ps[w][fr][32 + fg * 8];
      __builtin_amdgcn_s_setprio(1);
      #pragma unroll
      for (int nb = 0; nb < 4; ++nb) {
        const bf16x8 v0 = *(const bf16x8*)&VsT[nb * 16 + fr][fg * 8];
        const bf16x8 v1 = *(const bf16x8*)&VsT[nb * 16 + fr][32 + fg * 8];
        o[nb] = __builtin_amdgcn_mfma_f32_16x16x32_bf16(pa0, v0, o[nb], 0, 0, 0);
        o[nb] = __builtin_amdgcn_mfma_f32_16x16x32_bf16(pa1, v1, o[nb], 0, 0, 0);
      }
      __builtin_amdgcn_s_setprio(0);
    }
    __syncthreads();
  }
  for (int i = 0; i < 4; ++i) {
    const float inv = 1.0f / lrow[i];
    const size_t row = (size_t)(b * 1024 + qr + fg * 4 + i);
    for (int nb = 0; nb < 4; ++nb)
      O[row * 1024 + hcol + nb * 16 + fr] = f2bf(o[nb][i] * inv);
  }
}

// ---------------------------------------------------------------------------
extern "C" void kernel_launch(void* const* d_in, const int* in_sizes, int n_in,
                              void* d_out, int out_size, void* d_ws, size_t ws_size,
                              hipStream_t stream) {
  const float* dec  = (const float*)d_in[0];
  const float* enc  = (const float*)d_in[1];
  const float* sa_g = (const float*)d_in[4];
  const float* sa_b = (const float*)d_in[5];
  const float* sa_wq = (const float*)d_in[6];
  const float* sa_bq = (const float*)d_in[7];
  const float* sa_wk = (const float*)d_in[8];
  const float* sa_wv = (const float*)d_in[9];
  const float* sa_bv = (const float*)d_in[10];
  const float* sa_wo = (const float*)d_in[11];
  const float* sa_bo = (const float*)d_in[12];
  const float* ca_g = (const float*)d_in[13];
  const float* ca_b = (const float*)d_in[14];
  const float* ca_wq = (const float*)d_in[15];
  const float* ca_bq = (const float*)d_in[16];
  const float* ca_wk = (const float*)d_in[17];
  const float* ca_wv = (const float*)d_in[18];
  const float* ca_bv = (const float*)d_in[19];
  const float* ca_wo = (const float*)d_in[20];
  const float* ca_bo = (const float*)d_in[21];
  const float* mlp_g = (const float*)d_in[22];
  const float* mlp_b = (const float*)d_in[23];
  const float* w1 = (const float*)d_in[24];
  const float* b1 = (const float*)d_in[25];
  const float* w2 = (const float*)d_in[26];
  const float* b2 = (const float*)d_in[27];

  const size_t MB = 1024 * 1024;
  if (ws_size < 97 * MB) return;
  char* ws = (char*)d_ws;
  // persistent weights
  u16* WQKV = (u16*)(ws + 0 * MB);           // [3072][1024]
  u16* CQT  = (u16*)(ws + 6 * MB);           // [1024][1024]
  u16* CKV  = (u16*)(ws + 8 * MB);           // [2048][1024]
  u16* WOT  = (u16*)(ws + 12 * MB);
  u16* COT  = (u16*)(ws + 14 * MB);
  float* B3 = (float*)(ws + 16 * MB);        // 3072 f32
  float* B2 = (float*)(ws + 16 * MB + 16384);// 2048 f32
  // activations (aliased across stages)
  u16* XLN  = (u16*)(ws + 17 * MB);          // [4096][1024]
  u16* AO   = (u16*)(ws + 25 * MB);          // [4096][1024]; stage C: W1T
  u16* W1T  = (u16*)(ws + 25 * MB);          // [4096][1024] (stage C)
  u16* ENC  = (u16*)(ws + 33 * MB);          // [4096][1024]; stage C: part of H1
  u16* FB   = (u16*)(ws + 41 * MB);          // [4096][3072] (stage A)
  u16* EF   = (u16*)(ws + 41 * MB);          // [4096][2048] (stage B)
  u16* CQB  = (u16*)(ws + 57 * MB);          // [4096][1024] (stage B)
  u16* H1   = (u16*)(ws + 33 * MB);          // [4096][4096] (stage C, over ENC+FB)
  float* X1 = (float*)(ws + 65 * MB);        // [4096][1024] f32; stage C: W2T
  u16* W2T  = (u16*)(ws + 65 * MB);          // [1024][4096] (stage C)
  float* X2 = (float*)(ws + 81 * MB);        // [4096][1024] f32
  float* OUT = (float*)d_out;

  const dim3 blk(256), gblk(512);
  // ---- weight prep ----
  TC8 tc;
  tc.s[0] = sa_wq; tc.d[0] = WQKV;
  tc.s[1] = sa_wk; tc.d[1] = WQKV + 1024 * 1024;
  tc.s[2] = sa_wv; tc.d[2] = WQKV + 2048 * 1024;
  tc.s[3] = sa_wo; tc.d[3] = WOT;
  tc.s[4] = ca_wq; tc.d[4] = CQT;
  tc.s[5] = ca_wk; tc.d[5] = CKV;
  tc.s[6] = ca_wv; tc.d[6] = CKV + 1024 * 1024;
  tc.s[7] = ca_wo; tc.d[7] = COT;
  transcvt8_kernel<<<dim3(32, 32, 8), blk, 0, stream>>>(tc);
  pack_bias_kernel<<<dim3(20), blk, 0, stream>>>(sa_bq, sa_bv, ca_bv, B3, B2);
  cvt_kernel<<<dim3(4096), blk, 0, stream>>>(enc, ENC);

  // ---- self-attention block ----
  ln_kernel<<<dim3(4096), blk, 0, stream>>>(dec, sa_g, sa_b, XLN);
  gemm_kernel<false, false><<<dim3(24, 32), gblk, 0, stream>>>(XLN, WQKV, B3, nullptr, FB, 4096, 3072, 1024);
  attn_kernel<true><<<dim3(16, 64), blk, 0, stream>>>(FB, 3072, FB + 1024, 3072, FB + 2048, 3072, AO);
  gemm_kernel<true, false><<<dim3(8, 32), gblk, 0, stream>>>(AO, WOT, sa_bo, dec, X1, 4096, 1024, 1024);

  // ---- cross-attention block ----
  ln_kernel<<<dim3(4096), blk, 0, stream>>>(X1, ca_g, ca_b, XLN);
  gemm_kernel<false, false><<<dim3(16, 32), gblk, 0, stream>>>(ENC, CKV, B2, nullptr, EF, 4096, 2048, 1024);
  gemm_kernel<false, false><<<dim3(8, 32), gblk, 0, stream>>>(XLN, CQT, ca_bq, nullptr, CQB, 4096, 1024, 1024);
  attn_kernel<false><<<dim3(16, 64), blk, 0, stream>>>(CQB, 1024, EF, 2048, EF + 1024, 2048, AO);
  gemm_kernel<true, false><<<dim3(8, 32), gblk, 0, stream>>>(AO, COT, ca_bo, X1, X2, 4096, 1024, 1024);

  // ---- FFN block ----
  transcvt_kernel<<<dim3(128, 32), blk, 0, stream>>>(w1, W1T, 1024, 4096);
  transcvt_kernel<<<dim3(32, 128), blk, 0, stream>>>(w2, W2T, 4096, 1024);
  ln_kernel<<<dim3(4096), blk, 0, stream>>>(X2, mlp_g, mlp_b, XLN);
  gemm_kernel<false, true><<<dim3(32, 32), gblk, 0, stream>>>(XLN, W1T, b1, nullptr, H1, 4096, 4096, 1024);
  gemm_kernel<true, false><<<dim3(8, 32), gblk, 0, stream>>>(H1, W2T, b2, X2, OUT, 4096, 1024, 4096);
}

// Round 5
// 454.143 us; speedup vs baseline: 2.8063x; 1.0038x over previous
//
#include <hip/hip_runtime.h>
#include <math.h>

typedef unsigned short u16;
typedef unsigned int   u32;
typedef __attribute__((ext_vector_type(8))) short bf16x8;  // 8 bf16 (4 VGPRs)
typedef __attribute__((ext_vector_type(4))) float f32x4;

__device__ __forceinline__ u16 f2bf(float f) {
  u32 u = __builtin_bit_cast(u32, f);
  u += 0x7fffu + ((u >> 16) & 1u);   // RNE
  return (u16)(u >> 16);
}
__device__ __forceinline__ u32 pack2(float a, float b) {
  return (u32)f2bf(a) | ((u32)f2bf(b) << 16);
}

// async global->LDS, 16B per lane. LDS dest must be wave-uniform; HW writes
// lane l's 16B at dest + l*16 (linear). Global src is per-lane.
__device__ __forceinline__ void g2l16(const u16* g, u16* l) {
  __builtin_amdgcn_global_load_lds(
      (const __attribute__((address_space(1))) unsigned int*)g,
      (__attribute__((address_space(3))) unsigned int*)l, 16, 0, 0);
}

// ---------------- batched transpose+convert for 8x [1024][1024] weights ------
struct TC8 { const float* s[8]; u16* d[8]; };
__global__ __launch_bounds__(256)
void transcvt8_kernel(TC8 p) {
  const float* __restrict__ W = p.s[blockIdx.z];
  u16* __restrict__ Wt = p.d[blockIdx.z];
  __shared__ float tile[32][33];
  const int n0 = blockIdx.x * 32, k0 = blockIdx.y * 32;
  const int tx = threadIdx.x & 31, ty = threadIdx.x >> 5;  // 32 x 8
  for (int i = 0; i < 4; ++i)
    tile[ty + 8 * i][tx] = W[(size_t)(k0 + ty + 8 * i) * 1024 + n0 + tx];
  __syncthreads();
  for (int i = 0; i < 4; ++i)
    Wt[(size_t)(n0 + ty + 8 * i) * 1024 + k0 + tx] = f2bf(tile[tx][ty + 8 * i]);
}

// ---------------- transpose + convert: W[K][N] f32 -> Wt[N][K] bf16 ----------
__global__ __launch_bounds__(256)
void transcvt_kernel(const float* __restrict__ W, u16* __restrict__ Wt, int K, int N) {
  __shared__ float tile[32][33];
  const int n0 = blockIdx.x * 32, k0 = blockIdx.y * 32;
  const int tx = threadIdx.x & 31, ty = threadIdx.x >> 5;
  for (int i = 0; i < 4; ++i)
    tile[ty + 8 * i][tx] = W[(size_t)(k0 + ty + 8 * i) * N + n0 + tx];
  __syncthreads();
  for (int i = 0; i < 4; ++i)
    Wt[(size_t)(n0 + ty + 8 * i) * K + k0 + tx] = f2bf(tile[tx][ty + 8 * i]);
}

// ---------------- elementwise convert f32 -> bf16 ----------------------------
__global__ __launch_bounds__(256)
void cvt_kernel(const float* __restrict__ in, u16* __restrict__ out) {
  const int i = blockIdx.x * 256 + threadIdx.x;
  const float4 v = ((const float4*)in)[i];
  u16 o[4] = {f2bf(v.x), f2bf(v.y), f2bf(v.z), f2bf(v.w)};
  ((ushort4*)out)[i] = *(ushort4*)o;
}

// ---------------- bias packing (B3: [bq|0|bv], B2: [0|bv]) ------------------
__global__ __launch_bounds__(256)
void pack_bias_kernel(const float* __restrict__ bq, const float* __restrict__ bv,
                      const float* __restrict__ cbv,
                      float* __restrict__ B3, float* __restrict__ B2) {
  const int i = blockIdx.x * 256 + threadIdx.x;   // 5120 total
  if (i < 3072) {
    float v = 0.0f;
    if (i < 1024) v = bq[i];
    else if (i >= 2048) v = bv[i - 2048];
    B3[i] = v;
  } else {
    const int j = i - 3072;
    B2[j] = (j >= 1024) ? cbv[j - 1024] : 0.0f;
  }
}

// ---------------- LayerNorm: rows of 1024, f32 in -> bf16 out ---------------
__global__ __launch_bounds__(256)
void ln_kernel(const float* __restrict__ x, const float* __restrict__ g,
               const float* __restrict__ b, u16* __restrict__ out) {
  const int row = blockIdx.x;
  const float4 v4 = ((const float4*)(x + (size_t)row * 1024))[threadIdx.x];
  float vv[4] = {v4.x, v4.y, v4.z, v4.w};
  float s = vv[0] + vv[1] + vv[2] + vv[3];
  float s2 = vv[0] * vv[0] + vv[1] * vv[1] + vv[2] * vv[2] + vv[3] * vv[3];
  for (int m = 1; m < 64; m <<= 1) { s += __shfl_xor(s, m); s2 += __shfl_xor(s2, m); }
  __shared__ float ss[4], ss2[4];
  const int w = threadIdx.x >> 6;
  if ((threadIdx.x & 63) == 0) { ss[w] = s; ss2[w] = s2; }
  __syncthreads();
  s = ss[0] + ss[1] + ss[2] + ss[3];
  s2 = ss2[0] + ss2[1] + ss2[2] + ss2[3];
  const float mu = s * (1.0f / 1024.0f);
  const float var = s2 * (1.0f / 1024.0f) - mu * mu;
  const float r = rsqrtf(var + 1e-5f);
  const int c = threadIdx.x * 4;
  const float4 g4 = ((const float4*)g)[threadIdx.x];
  const float4 b4 = ((const float4*)b)[threadIdx.x];
  float gg[4] = {g4.x, g4.y, g4.z, g4.w};
  float bb[4] = {b4.x, b4.y, b4.z, b4.w};
  u16 o[4];
  for (int j = 0; j < 4; ++j) o[j] = f2bf((vv[j] - mu) * r * gg[j] + bb[j]);
  ((ushort4*)(out + (size_t)row * 1024 + c))[0] = *(ushort4*)o;
}

// ---------------- GEMM: 128x128 tile, 8 waves (512 thr), 2-phase dbuf -------
// C = act(A[M,K] @ Bt[N,K]^T + bias) (+res). Wave grid 2x4; wave = 64x32 out.
// XCD-aware block swizzle (requires nwg % 8 == 0, all our grids satisfy).
template<bool RES_F32, bool GELU>
__global__ __launch_bounds__(512)
void gemm_kernel(const u16* __restrict__ A, const u16* __restrict__ Bt,
                 const float* __restrict__ bias, const float* __restrict__ res,
                 void* __restrict__ Cout, int M, int N, int K) {
  __shared__ u16 As[2][128][32];
  __shared__ u16 Bs[2][128][32];
  const int t = threadIdx.x, lane = t & 63, w = t >> 6;
  const int wr = w >> 2, wc = w & 3;
  const int nwg = gridDim.x * gridDim.y;
  int bid = blockIdx.y * gridDim.x + blockIdx.x;
  bid = (bid & 7) * (nwg >> 3) + (bid >> 3);
  const int m0 = (bid / gridDim.x) * 128, n0 = (bid % gridDim.x) * 128;
  const int fr = lane & 15, fg = lane >> 4;
  const int srow = lane >> 2, scol = (lane & 3) * 8;
  const u16* Ag = &A[(size_t)(m0 + w * 16 + srow) * K + scol];
  const u16* Bg = &Bt[(size_t)(n0 + w * 16 + srow) * K + scol];
  f32x4 acc[4][2] = {};
  g2l16(Ag, &As[0][w * 16][0]);
  g2l16(Bg, &Bs[0][w * 16][0]);
  __syncthreads();
  int cur = 0;
  for (int k0 = 0; k0 < K; k0 += 32) {
    if (k0 + 32 < K) {
      const int nx = cur ^ 1, kn = k0 + 32;
      g2l16(Ag + kn, &As[nx][w * 16][0]);
      g2l16(Bg + kn, &Bs[nx][w * 16][0]);
    }
    bf16x8 af[4], bfr[2];
    for (int m = 0; m < 4; ++m) af[m] = *(bf16x8*)&As[cur][wr * 64 + m * 16 + fr][fg * 8];
    for (int n = 0; n < 2; ++n) bfr[n] = *(bf16x8*)&Bs[cur][wc * 32 + n * 16 + fr][fg * 8];
    __builtin_amdgcn_s_setprio(1);
    for (int m = 0; m < 4; ++m)
      for (int n = 0; n < 2; ++n)
        acc[m][n] = __builtin_amdgcn_mfma_f32_16x16x32_bf16(af[m], bfr[n], acc[m][n], 0, 0, 0);
    __builtin_amdgcn_s_setprio(0);
    __syncthreads();
    cur ^= 1;
  }
  for (int m = 0; m < 4; ++m)
    for (int n = 0; n < 2; ++n) {
      const int col = n0 + wc * 32 + n * 16 + fr;
      const float bv = bias ? bias[col] : 0.0f;
      for (int i = 0; i < 4; ++i) {
        const int row = m0 + wr * 64 + m * 16 + fg * 4 + i;
        float v = acc[m][n][i] + bv;
        if (GELU) v = 0.5f * v * (1.0f + erff(v * 0.70710678118654752f));
        if (RES_F32)
          ((float*)Cout)[(size_t)row * N + col] = res[(size_t)row * N + col] + v;
        else
          ((u16*)Cout)[(size_t)row * N + col] = f2bf(v);
      }
    }
}

// ---------------- Flash attention, swapped-QK^T (S^T = K·Q^T) ---------------
// grid (T/64, B*H), 256 thr = 4 waves x 16 q-rows. KVBLK=64.
// Per lane: q = lane&15 fixed; scores/P are lane-local -> 2-shuffle max reduce
// (deferred via T13), deferred sum, u32 P-pack to wave-private LDS.
// V^T staged in XOR-swizzled LDS (conflict-free writes, 2-way b128 reads),
// double-buffered -> ONE block barrier per k-tile.
template<bool CAUSAL>
__global__ __launch_bounds__(256)
void attn_kernel(const u16* __restrict__ Q, int ldq,
                 const u16* __restrict__ K, int ldk,
                 const u16* __restrict__ V, int ldv,
                 u16* __restrict__ O) {
  __shared__ u16 VsT[2][64][64];   // [buf][dim][key ^ swz]
  __shared__ u16 Ps[4][16][72];    // [wave][q][key], stride 72 u16 (144B)
  const int bh = blockIdx.y, b = bh >> 4, h = bh & 15;
  const int q0 = blockIdx.x * 64;
  const int t = threadIdx.x, w = t >> 6, lane = t & 63;
  const int ql = lane & 15;        // this lane's q (within wave block)
  const int hi = lane >> 4;        // 0..3
  const int qr = q0 + w * 16;
  const int qz = qr + ql;          // absolute q row for scores
  const int hcol = h * 64;
  // Q B-fragment: lane holds Q[qz][hcol + kk*32 + hi*8 + j]
  const size_t qgrow = (size_t)(b * 1024 + qz) * ldq + hcol;
  bf16x8 qb[2];
  qb[0] = *(const bf16x8*)&Q[qgrow + hi * 8];
  qb[1] = *(const bf16x8*)&Q[qgrow + 32 + hi * 8];
  f32x4 o[4] = {};
  float mrow = -1e30f;   // running max (exp2 domain), uniform across hi-group
  float lsum = 0.0f;     // per-lane partial sum
  // V staging map: thread -> key pair 2sp, dim octet 8sm
  const int sp = t >> 3, sm = t & 7;
  const float c1 = 0.125f * 1.44269504f;   // scale * log2(e)
  const int nkt = CAUSAL ? (blockIdx.x + 1) : 16;
  {  // prologue: stage V tile 0 into buf 0
    const bf16x8 va = *(const bf16x8*)&V[(size_t)(b * 1024 + 2 * sp) * ldv + hcol + 8 * sm];
    const bf16x8 vb = *(const bf16x8*)&V[(size_t)(b * 1024 + 2 * sp + 1) * ldv + hcol + 8 * sm];
    #pragma unroll
    for (int jj = 0; jj < 8; ++jj) {
      u32 pr = (u32)((const u16*)&va)[jj] | ((u32)((const u16*)&vb)[jj] << 16);
      *(u32*)&VsT[0][8 * sm + jj][(2 * sp) ^ ((jj ^ sm) << 3)] = pr;
    }
  }
  __syncthreads();
  int cur = 0;
  for (int kt = 0; kt < nkt; ++kt) {
    const int k0 = kt * 64;
    // T14: issue next V-tile global loads early (consumed after PV)
    bf16x8 va, vb;
    const bool havenext = (kt + 1 < nkt);
    if (havenext) {
      va = *(const bf16x8*)&V[(size_t)(b * 1024 + k0 + 64 + 2 * sp) * ldv + hcol + 8 * sm];
      vb = *(const bf16x8*)&V[(size_t)(b * 1024 + k0 + 64 + 2 * sp + 1) * ldv + hcol + 8 * sm];
    }
    // QK^T swapped: s[j] = K_j · Q^T  (D[key][q], q = ql per lane)
    f32x4 s[4] = {};
    #pragma unroll
    for (int kk = 0; kk < 2; ++kk) {
      bf16x8 kf[4];
      #pragma unroll
      for (int j = 0; j < 4; ++j)
        kf[j] = *(const bf16x8*)&K[(size_t)(b * 1024 + k0 + j * 16 + ql) * ldk + hcol + kk * 32 + hi * 8];
      __builtin_amdgcn_s_setprio(1);
      #pragma unroll
      for (int j = 0; j < 4; ++j)
        s[j] = __builtin_amdgcn_mfma_f32_16x16x32_bf16(kf[j], qb[kk], s[j], 0, 0, 0);
      __builtin_amdgcn_s_setprio(0);
    }
    // softmax (exp2 domain), defer-max
    float e2[4][4];
    float rm = -1e30f;
    const bool domask = CAUSAL && (kt == nkt - 1);
    #pragma unroll
    for (int j = 0; j < 4; ++j)
      #pragma unroll
      for (int i = 0; i < 4; ++i) {
        float a = s[j][i] * c1;
        if (domask && (k0 + j * 16 + hi * 4 + i > qz)) a = -1e30f;
        e2[j][i] = a;
        rm = fmaxf(rm, a);
      }
    if (!__all(rm <= mrow + 8.0f)) {
      rm = fmaxf(rm, __shfl_xor(rm, 16));
      rm = fmaxf(rm, __shfl_xor(rm, 32));
      const float mn = fmaxf(mrow, rm);
      const float sc = exp2f(mrow - mn);
      lsum *= sc;
      float scv[4];
      #pragma unroll
      for (int i = 0; i < 4; ++i) scv[i] = __shfl(sc, hi * 4 + i);
      #pragma unroll
      for (int nb = 0; nb < 4; ++nb)
        #pragma unroll
        for (int i = 0; i < 4; ++i) o[nb][i] *= scv[i];
      mrow = mn;
    }
    float p[4][4];
    #pragma unroll
    for (int j = 0; j < 4; ++j)
      #pragma unroll
      for (int i = 0; i < 4; ++i) { p[j][i] = exp2f(e2[j][i] - mrow); lsum += p[j][i]; }
    // P -> wave-private LDS (u32 pairs; keys hi*4+i consecutive in i)
    #pragma unroll
    for (int j = 0; j < 4; ++j) {
      *(u32*)&Ps[w][ql][j * 16 + hi * 4]     = pack2(p[j][0], p[j][1]);
      *(u32*)&Ps[w][ql][j * 16 + hi * 4 + 2] = pack2(p[j][2], p[j][3]);
    }
    asm volatile("s_waitcnt lgkmcnt(0)" ::: "memory");
    __builtin_amdgcn_sched_barrier(0);
    // PV: A = P[16q x 32k] (b128 from Ps), B = V[32k x 16d] (b128 from VsT)
    bf16x8 pa[2];
    pa[0] = *(const bf16x8*)&Ps[w][ql][hi * 8];
    pa[1] = *(const bf16x8*)&Ps[w][ql][32 + hi * 8];
    __builtin_amdgcn_s_setprio(1);
    #pragma unroll
    for (int nb = 0; nb < 4; ++nb) {
      const int dim = nb * 16 + ql;
      const int swz = ((dim & 7) ^ ((dim >> 3) & 7)) << 3;
      const bf16x8 v0 = *(const bf16x8*)&VsT[cur][dim][(hi * 8) ^ swz];
      const bf16x8 v1 = *(const bf16x8*)&VsT[cur][dim][(32 + hi * 8) ^ swz];
      o[nb] = __builtin_amdgcn_mfma_f32_16x16x32_bf16(pa[0], v0, o[nb], 0, 0, 0);
      o[nb] = __builtin_amdgcn_mfma_f32_16x16x32_bf16(pa[1], v1, o[nb], 0, 0, 0);
    }
    __builtin_amdgcn_s_setprio(0);
    // finish staging next V tile (write-late)
    if (havenext) {
      const int nx = cur ^ 1;
      #pragma unroll
      for (int jj = 0; jj < 8; ++jj) {
        u32 pr = (u32)((const u16*)&va)[jj] | ((u32)((const u16*)&vb)[jj] << 16);
        *(u32*)&VsT[nx][8 * sm + jj][(2 * sp) ^ ((jj ^ sm) << 3)] = pr;
      }
    }
    __syncthreads();
    cur ^= 1;
  }
  // final: reduce per-lane partial sums across the hi-group (2 shuffles)
  float ltot = lsum + __shfl_xor(lsum, 16);
  ltot += __shfl_xor(ltot, 32);
  const float inv = 1.0f / ltot;   // valid for q = qz
  #pragma unroll
  for (int i = 0; i < 4; ++i) {
    const float invq = __shfl(inv, hi * 4 + i);   // factor for output row qr+hi*4+i
    const size_t row = (size_t)(b * 1024 + qr + hi * 4 + i);
    #pragma unroll
    for (int nb = 0; nb < 4; ++nb)
      O[row * 1024 + hcol + nb * 16 + ql] = f2bf(o[nb][i] * invq);
  }
}

// ---------------------------------------------------------------------------
extern "C" void kernel_launch(void* const* d_in, const int* in_sizes, int n_in,
                              void* d_out, int out_size, void* d_ws, size_t ws_size,
                              hipStream_t stream) {
  const float* dec  = (const float*)d_in[0];
  const float* enc  = (const float*)d_in[1];
  const float* sa_g = (const float*)d_in[4];
  const float* sa_b = (const float*)d_in[5];
  const float* sa_wq = (const float*)d_in[6];
  const float* sa_bq = (const float*)d_in[7];
  const float* sa_wk = (const float*)d_in[8];
  const float* sa_wv = (const float*)d_in[9];
  const float* sa_bv = (const float*)d_in[10];
  const float* sa_wo = (const float*)d_in[11];
  const float* sa_bo = (const float*)d_in[12];
  const float* ca_g = (const float*)d_in[13];
  const float* ca_b = (const float*)d_in[14];
  const float* ca_wq = (const float*)d_in[15];
  const float* ca_bq = (const float*)d_in[16];
  const float* ca_wk = (const float*)d_in[17];
  const float* ca_wv = (const float*)d_in[18];
  const float* ca_bv = (const float*)d_in[19];
  const float* ca_wo = (const float*)d_in[20];
  const float* ca_bo = (const float*)d_in[21];
  const float* mlp_g = (const float*)d_in[22];
  const float* mlp_b = (const float*)d_in[23];
  const float* w1 = (const float*)d_in[24];
  const float* b1 = (const float*)d_in[25];
  const float* w2 = (const float*)d_in[26];
  const float* b2 = (const float*)d_in[27];

  const size_t MB = 1024 * 1024;
  if (ws_size < 97 * MB) return;
  char* ws = (char*)d_ws;
  // persistent weights
  u16* WQKV = (u16*)(ws + 0 * MB);           // [3072][1024]
  u16* CQT  = (u16*)(ws + 6 * MB);           // [1024][1024]
  u16* CKV  = (u16*)(ws + 8 * MB);           // [2048][1024]
  u16* WOT  = (u16*)(ws + 12 * MB);
  u16* COT  = (u16*)(ws + 14 * MB);
  float* B3 = (float*)(ws + 16 * MB);        // 3072 f32
  float* B2 = (float*)(ws + 16 * MB + 16384);// 2048 f32
  // activations (aliased across stages)
  u16* XLN  = (u16*)(ws + 17 * MB);          // [4096][1024]
  u16* AO   = (u16*)(ws + 25 * MB);          // [4096][1024]; stage C: W1T
  u16* W1T  = (u16*)(ws + 25 * MB);          // [4096][1024] (stage C)
  u16* ENC  = (u16*)(ws + 33 * MB);          // [4096][1024]; stage C: part of H1
  u16* FB   = (u16*)(ws + 41 * MB);          // [4096][3072] (stage A)
  u16* EF   = (u16*)(ws + 41 * MB);          // [4096][2048] (stage B)
  u16* CQB  = (u16*)(ws + 57 * MB);          // [4096][1024] (stage B)
  u16* H1   = (u16*)(ws + 33 * MB);          // [4096][4096] (stage C, over ENC+FB)
  float* X1 = (float*)(ws + 65 * MB);        // [4096][1024] f32; stage C: W2T
  u16* W2T  = (u16*)(ws + 65 * MB);          // [1024][4096] (stage C)
  float* X2 = (float*)(ws + 81 * MB);        // [4096][1024] f32
  float* OUT = (float*)d_out;

  const dim3 blk(256), gblk(512);
  // ---- weight prep ----
  TC8 tc;
  tc.s[0] = sa_wq; tc.d[0] = WQKV;
  tc.s[1] = sa_wk; tc.d[1] = WQKV + 1024 * 1024;
  tc.s[2] = sa_wv; tc.d[2] = WQKV + 2048 * 1024;
  tc.s[3] = sa_wo; tc.d[3] = WOT;
  tc.s[4] = ca_wq; tc.d[4] = CQT;
  tc.s[5] = ca_wk; tc.d[5] = CKV;
  tc.s[6] = ca_wv; tc.d[6] = CKV + 1024 * 1024;
  tc.s[7] = ca_wo; tc.d[7] = COT;
  transcvt8_kernel<<<dim3(32, 32, 8), blk, 0, stream>>>(tc);
  pack_bias_kernel<<<dim3(20), blk, 0, stream>>>(sa_bq, sa_bv, ca_bv, B3, B2);
  cvt_kernel<<<dim3(4096), blk, 0, stream>>>(enc, ENC);

  // ---- self-attention block ----
  ln_kernel<<<dim3(4096), blk, 0, stream>>>(dec, sa_g, sa_b, XLN);
  gemm_kernel<false, false><<<dim3(24, 32), gblk, 0, stream>>>(XLN, WQKV, B3, nullptr, FB, 4096, 3072, 1024);
  attn_kernel<true><<<dim3(16, 64), blk, 0, stream>>>(FB, 3072, FB + 1024, 3072, FB + 2048, 3072, AO);
  gemm_kernel<true, false><<<dim3(8, 32), gblk, 0, stream>>>(AO, WOT, sa_bo, dec, X1, 4096, 1024, 1024);

  // ---- cross-attention block ----
  ln_kernel<<<dim3(4096), blk, 0, stream>>>(X1, ca_g, ca_b, XLN);
  gemm_kernel<false, false><<<dim3(16, 32), gblk, 0, stream>>>(ENC, CKV, B2, nullptr, EF, 4096, 2048, 1024);
  gemm_kernel<false, false><<<dim3(8, 32), gblk, 0, stream>>>(XLN, CQT, ca_bq, nullptr, CQB, 4096, 1024, 1024);
  attn_kernel<false><<<dim3(16, 64), blk, 0, stream>>>(CQB, 1024, EF, 2048, EF + 1024, 2048, AO);
  gemm_kernel<true, false><<<dim3(8, 32), gblk, 0, stream>>>(AO, COT, ca_bo, X1, X2, 4096, 1024, 1024);

  // ---- FFN block ----
  transcvt_kernel<<<dim3(128, 32), blk, 0, stream>>>(w1, W1T, 1024, 4096);
  transcvt_kernel<<<dim3(32, 128), blk, 0, stream>>>(w2, W2T, 4096, 1024);
  ln_kernel<<<dim3(4096), blk, 0, stream>>>(X2, mlp_g, mlp_b, XLN);
  gemm_kernel<false, true><<<dim3(32, 32), gblk, 0, stream>>>(XLN, W1T, b1, nullptr, H1, 4096, 4096, 1024);
  gemm_kernel<true, false><<<dim3(8, 32), gblk, 0, stream>>>(H1, W2T, b2, X2, OUT, 4096, 1024, 4096);
}

// Round 6
// 451.548 us; speedup vs baseline: 2.8224x; 1.0057x over previous
//
#include <hip/hip_runtime.h>
#include <math.h>

typedef unsigned short u16;
typedef unsigned int   u32;
typedef __attribute__((ext_vector_type(8))) short bf16x8;  // 8 bf16 (4 VGPRs)
typedef __attribute__((ext_vector_type(4))) float f32x4;

__device__ __forceinline__ u16 f2bf(float f) {
  u32 u = __builtin_bit_cast(u32, f);
  u += 0x7fffu + ((u >> 16) & 1u);   // RNE
  return (u16)(u >> 16);
}
__device__ __forceinline__ u32 cvtpk(float lo, float hi_) {
  u32 r;
  asm("v_cvt_pk_bf16_f32 %0, %1, %2" : "=v"(r) : "v"(lo), "v"(hi_));
  return r;
}

// async global->LDS, 16B per lane. LDS dest must be wave-uniform; HW writes
// lane l's 16B at dest + l*16 (linear). Global src is per-lane.
__device__ __forceinline__ void g2l16(const u16* g, u16* l) {
  __builtin_amdgcn_global_load_lds(
      (const __attribute__((address_space(1))) unsigned int*)g,
      (__attribute__((address_space(3))) unsigned int*)l, 16, 0, 0);
}

// ---------------- batched transpose+convert for 8x [1024][1024] weights ------
struct TC8 { const float* s[8]; u16* d[8]; };
__global__ __launch_bounds__(256)
void transcvt8_kernel(TC8 p) {
  const float* __restrict__ W = p.s[blockIdx.z];
  u16* __restrict__ Wt = p.d[blockIdx.z];
  __shared__ float tile[32][33];
  const int n0 = blockIdx.x * 32, k0 = blockIdx.y * 32;
  const int tx = threadIdx.x & 31, ty = threadIdx.x >> 5;  // 32 x 8
  for (int i = 0; i < 4; ++i)
    tile[ty + 8 * i][tx] = W[(size_t)(k0 + ty + 8 * i) * 1024 + n0 + tx];
  __syncthreads();
  for (int i = 0; i < 4; ++i)
    Wt[(size_t)(n0 + ty + 8 * i) * 1024 + k0 + tx] = f2bf(tile[tx][ty + 8 * i]);
}

// ---------------- transpose + convert: W[K][N] f32 -> Wt[N][K] bf16 ----------
__global__ __launch_bounds__(256)
void transcvt_kernel(const float* __restrict__ W, u16* __restrict__ Wt, int K, int N) {
  __shared__ float tile[32][33];
  const int n0 = blockIdx.x * 32, k0 = blockIdx.y * 32;
  const int tx = threadIdx.x & 31, ty = threadIdx.x >> 5;
  for (int i = 0; i < 4; ++i)
    tile[ty + 8 * i][tx] = W[(size_t)(k0 + ty + 8 * i) * N + n0 + tx];
  __syncthreads();
  for (int i = 0; i < 4; ++i)
    Wt[(size_t)(n0 + ty + 8 * i) * K + k0 + tx] = f2bf(tile[tx][ty + 8 * i]);
}

// ---------------- elementwise convert f32 -> bf16 ----------------------------
__global__ __launch_bounds__(256)
void cvt_kernel(const float* __restrict__ in, u16* __restrict__ out) {
  const int i = blockIdx.x * 256 + threadIdx.x;
  const float4 v = ((const float4*)in)[i];
  u16 o[4] = {f2bf(v.x), f2bf(v.y), f2bf(v.z), f2bf(v.w)};
  ((ushort4*)out)[i] = *(ushort4*)o;
}

// ---------------- bias packing (B3: [bq|0|bv], B2: [0|bv]) ------------------
__global__ __launch_bounds__(256)
void pack_bias_kernel(const float* __restrict__ bq, const float* __restrict__ bv,
                      const float* __restrict__ cbv,
                      float* __restrict__ B3, float* __restrict__ B2) {
  const int i = blockIdx.x * 256 + threadIdx.x;   // 5120 total
  if (i < 3072) {
    float v = 0.0f;
    if (i < 1024) v = bq[i];
    else if (i >= 2048) v = bv[i - 2048];
    B3[i] = v;
  } else {
    const int j = i - 3072;
    B2[j] = (j >= 1024) ? cbv[j - 1024] : 0.0f;
  }
}

// ---------------- LayerNorm: rows of 1024, f32 in -> bf16 out ---------------
__global__ __launch_bounds__(256)
void ln_kernel(const float* __restrict__ x, const float* __restrict__ g,
               const float* __restrict__ b, u16* __restrict__ out) {
  const int row = blockIdx.x;
  const float4 v4 = ((const float4*)(x + (size_t)row * 1024))[threadIdx.x];
  float vv[4] = {v4.x, v4.y, v4.z, v4.w};
  float s = vv[0] + vv[1] + vv[2] + vv[3];
  float s2 = vv[0] * vv[0] + vv[1] * vv[1] + vv[2] * vv[2] + vv[3] * vv[3];
  for (int m = 1; m < 64; m <<= 1) { s += __shfl_xor(s, m); s2 += __shfl_xor(s2, m); }
  __shared__ float ss[4], ss2[4];
  const int w = threadIdx.x >> 6;
  if ((threadIdx.x & 63) == 0) { ss[w] = s; ss2[w] = s2; }
  __syncthreads();
  s = ss[0] + ss[1] + ss[2] + ss[3];
  s2 = ss2[0] + ss2[1] + ss2[2] + ss2[3];
  const float mu = s * (1.0f / 1024.0f);
  const float var = s2 * (1.0f / 1024.0f) - mu * mu;
  const float r = rsqrtf(var + 1e-5f);
  const int c = threadIdx.x * 4;
  const float4 g4 = ((const float4*)g)[threadIdx.x];
  const float4 b4 = ((const float4*)b)[threadIdx.x];
  float gg[4] = {g4.x, g4.y, g4.z, g4.w};
  float bb[4] = {b4.x, b4.y, b4.z, b4.w};
  u16 o[4];
  for (int j = 0; j < 4; ++j) o[j] = f2bf((vv[j] - mu) * r * gg[j] + bb[j]);
  ((ushort4*)(out + (size_t)row * 1024 + c))[0] = *(ushort4*)o;
}

// ---------------- GEMM: 128x128 tile, 8 waves (512 thr), 2-phase dbuf -------
// (unchanged from round 5)
template<bool RES_F32, bool GELU>
__global__ __launch_bounds__(512)
void gemm_kernel(const u16* __restrict__ A, const u16* __restrict__ Bt,
                 const float* __restrict__ bias, const float* __restrict__ res,
                 void* __restrict__ Cout, int M, int N, int K) {
  __shared__ u16 As[2][128][32];
  __shared__ u16 Bs[2][128][32];
  const int t = threadIdx.x, lane = t & 63, w = t >> 6;
  const int wr = w >> 2, wc = w & 3;
  const int nwg = gridDim.x * gridDim.y;
  int bid = blockIdx.y * gridDim.x + blockIdx.x;
  bid = (bid & 7) * (nwg >> 3) + (bid >> 3);
  const int m0 = (bid / gridDim.x) * 128, n0 = (bid % gridDim.x) * 128;
  const int fr = lane & 15, fg = lane >> 4;
  const int srow = lane >> 2, scol = (lane & 3) * 8;
  const u16* Ag = &A[(size_t)(m0 + w * 16 + srow) * K + scol];
  const u16* Bg = &Bt[(size_t)(n0 + w * 16 + srow) * K + scol];
  f32x4 acc[4][2] = {};
  g2l16(Ag, &As[0][w * 16][0]);
  g2l16(Bg, &Bs[0][w * 16][0]);
  __syncthreads();
  int cur = 0;
  for (int k0 = 0; k0 < K; k0 += 32) {
    if (k0 + 32 < K) {
      const int nx = cur ^ 1, kn = k0 + 32;
      g2l16(Ag + kn, &As[nx][w * 16][0]);
      g2l16(Bg + kn, &Bs[nx][w * 16][0]);
    }
    bf16x8 af[4], bfr[2];
    for (int m = 0; m < 4; ++m) af[m] = *(bf16x8*)&As[cur][wr * 64 + m * 16 + fr][fg * 8];
    for (int n = 0; n < 2; ++n) bfr[n] = *(bf16x8*)&Bs[cur][wc * 32 + n * 16 + fr][fg * 8];
    __builtin_amdgcn_s_setprio(1);
    for (int m = 0; m < 4; ++m)
      for (int n = 0; n < 2; ++n)
        acc[m][n] = __builtin_amdgcn_mfma_f32_16x16x32_bf16(af[m], bfr[n], acc[m][n], 0, 0, 0);
    __builtin_amdgcn_s_setprio(0);
    __syncthreads();
    cur ^= 1;
  }
  for (int m = 0; m < 4; ++m)
    for (int n = 0; n < 2; ++n) {
      const int col = n0 + wc * 32 + n * 16 + fr;
      const float bv = bias ? bias[col] : 0.0f;
      for (int i = 0; i < 4; ++i) {
        const int row = m0 + wr * 64 + m * 16 + fg * 4 + i;
        float v = acc[m][n][i] + bv;
        if (GELU) v = 0.5f * v * (1.0f + erff(v * 0.70710678118654752f));
        if (RES_F32)
          ((float*)Cout)[(size_t)row * N + col] = res[(size_t)row * N + col] + v;
        else
          ((u16*)Cout)[(size_t)row * N + col] = f2bf(v);
      }
    }
}

// ---------------- Flash attention, swapped-QK^T, QBLK=128, K-prefetch -------
// grid (BH=64 on x -> XCD colocation, 8 q-tiles on y), 512 thr = 8 waves x 16 q.
// KVBLK=64. K double-buffered in REGISTERS (1 tile ahead); V dbuf in LDS.
// Causal: wave-uniform tile skip (wlim); mask only on the diagonal tile.
template<bool CAUSAL>
__global__ __launch_bounds__(512)
void attn_kernel(const u16* __restrict__ Q, int ldq,
                 const u16* __restrict__ K, int ldk,
                 const u16* __restrict__ V, int ldv,
                 u16* __restrict__ O) {
  __shared__ u16 VsT[2][64][64];   // [buf][dim][key ^ swz]
  __shared__ u16 Ps[8][16][72];    // [wave][q][key], stride 72 u16 (144B)
  const int bh = blockIdx.x, b = bh >> 4, h = bh & 15;
  const int qy = blockIdx.y;
  const int t = threadIdx.x, w = t >> 6, lane = t & 63;
  const int ql = lane & 15;        // this lane's q column
  const int hi = lane >> 4;        // 0..3
  const int qr = qy * 128 + w * 16;
  const int qz = qr + ql;
  const int hcol = h * 64;
  const int nkt = CAUSAL ? 2 * qy + 2 : 16;
  const int wlim = CAUSAL ? (qr >> 6) : nkt - 1;   // last tile this wave computes
  const u16* Kb = K + (size_t)(b * 1024) * ldk + hcol;
  const u16* Vb = V + (size_t)(b * 1024) * ldv + hcol;
  const size_t qgrow = (size_t)(b * 1024 + qz) * ldq + hcol;
  const bf16x8 qb0 = *(const bf16x8*)&Q[qgrow + hi * 8];
  const bf16x8 qb1 = *(const bf16x8*)&Q[qgrow + 32 + hi * 8];
  f32x4 o[4] = {};
  float mrow = -1e30f, lsum = 0.0f;
  const int sp = t >> 3, sm = t & 7;   // V staging map (threads t<256)
  const float c1 = 0.125f * 1.44269504f;   // scale * log2(e)
  // prologue: V tile 0 -> LDS buf 0; K tile 0 -> regs kA
  if (t < 256) {
    const bf16x8 va = *(const bf16x8*)&Vb[(size_t)(2 * sp) * ldv + 8 * sm];
    const bf16x8 vb = *(const bf16x8*)&Vb[(size_t)(2 * sp + 1) * ldv + 8 * sm];
    #pragma unroll
    for (int jj = 0; jj < 8; ++jj) {
      u32 pr = (u32)((const u16*)&va)[jj] | ((u32)((const u16*)&vb)[jj] << 16);
      *(u32*)&VsT[0][8 * sm + jj][(2 * sp) ^ ((jj ^ sm) << 3)] = pr;
    }
  }
  bf16x8 kA[8], kB[8];
  #pragma unroll
  for (int j = 0; j < 4; ++j) {
    kA[j]     = *(const bf16x8*)&Kb[(size_t)(j * 16 + ql) * ldk + hi * 8];
    kA[4 + j] = *(const bf16x8*)&Kb[(size_t)(j * 16 + ql) * ldk + 32 + hi * 8];
  }
  __syncthreads();

  auto body = [&](bf16x8 (&kc)[8], bf16x8 (&kn)[8], const int kt) {
    const int k0 = kt * 64;
    bf16x8 va, vb;
    const bool stageV = (kt + 1 < nkt) && (t < 256);
    if (stageV) {   // T14: issue next V loads early
      va = *(const bf16x8*)&Vb[(size_t)(k0 + 64 + 2 * sp) * ldv + 8 * sm];
      vb = *(const bf16x8*)&Vb[(size_t)(k0 + 64 + 2 * sp + 1) * ldv + 8 * sm];
    }
    if (kt + 1 <= wlim) {   // prefetch next K tile into kn (used next iter)
      #pragma unroll
      for (int j = 0; j < 4; ++j) {
        kn[j]     = *(const bf16x8*)&Kb[(size_t)(k0 + 64 + j * 16 + ql) * ldk + hi * 8];
        kn[4 + j] = *(const bf16x8*)&Kb[(size_t)(k0 + 64 + j * 16 + ql) * ldk + 32 + hi * 8];
      }
    }
    if (kt <= wlim) {
      // QK^T swapped: D[key][q], q = ql per lane
      f32x4 s[4] = {};
      __builtin_amdgcn_s_setprio(1);
      #pragma unroll
      for (int j = 0; j < 4; ++j)
        s[j] = __builtin_amdgcn_mfma_f32_16x16x32_bf16(kc[j], qb0, s[j], 0, 0, 0);
      #pragma unroll
      for (int j = 0; j < 4; ++j)
        s[j] = __builtin_amdgcn_mfma_f32_16x16x32_bf16(kc[4 + j], qb1, s[j], 0, 0, 0);
      __builtin_amdgcn_s_setprio(0);
      float e2[4][4];
      float rm = -1e30f;
      const bool domask = CAUSAL && (kt == wlim);
      #pragma unroll
      for (int j = 0; j < 4; ++j)
        #pragma unroll
        for (int i = 0; i < 4; ++i) {
          float a = s[j][i] * c1;
          if (domask && (k0 + j * 16 + hi * 4 + i > qz)) a = -1e30f;
          e2[j][i] = a;
          rm = fmaxf(rm, a);
        }
      if (!__all(rm <= mrow + 8.0f)) {   // T13 defer-max
        rm = fmaxf(rm, __shfl_xor(rm, 16));
        rm = fmaxf(rm, __shfl_xor(rm, 32));
        const float mn = fmaxf(mrow, rm);
        const float sc = exp2f(mrow - mn);
        lsum *= sc;
        float scv[4];
        #pragma unroll
        for (int i = 0; i < 4; ++i) scv[i] = __shfl(sc, hi * 4 + i);
        #pragma unroll
        for (int nb = 0; nb < 4; ++nb)
          #pragma unroll
          for (int i = 0; i < 4; ++i) o[nb][i] *= scv[i];
        mrow = mn;
      }
      float p[4][4];
      #pragma unroll
      for (int j = 0; j < 4; ++j)
        #pragma unroll
        for (int i = 0; i < 4; ++i) { p[j][i] = exp2f(e2[j][i] - mrow); lsum += p[j][i]; }
      #pragma unroll
      for (int j = 0; j < 4; ++j) {   // P -> wave-private LDS (cvt_pk pairs)
        *(u32*)&Ps[w][ql][j * 16 + hi * 4]     = cvtpk(p[j][0], p[j][1]);
        *(u32*)&Ps[w][ql][j * 16 + hi * 4 + 2] = cvtpk(p[j][2], p[j][3]);
      }
      asm volatile("s_waitcnt lgkmcnt(0)" ::: "memory");
      __builtin_amdgcn_sched_barrier(0);
      const bf16x8 pa0 = *(const bf16x8*)&Ps[w][ql][hi * 8];
      const bf16x8 pa1 = *(const bf16x8*)&Ps[w][ql][32 + hi * 8];
      __builtin_amdgcn_s_setprio(1);
      #pragma unroll
      for (int nb = 0; nb < 4; ++nb) {
        const int dim = nb * 16 + ql;
        const int swz = ((dim & 7) ^ ((dim >> 3) & 7)) << 3;
        const bf16x8 v0 = *(const bf16x8*)&VsT[kt & 1][dim][(hi * 8) ^ swz];
        const bf16x8 v1 = *(const bf16x8*)&VsT[kt & 1][dim][(32 + hi * 8) ^ swz];
        o[nb] = __builtin_amdgcn_mfma_f32_16x16x32_bf16(pa0, v0, o[nb], 0, 0, 0);
        o[nb] = __builtin_amdgcn_mfma_f32_16x16x32_bf16(pa1, v1, o[nb], 0, 0, 0);
      }
      __builtin_amdgcn_s_setprio(0);
    }
    if (stageV) {   // write-late into the other buffer
      const int nx = (kt & 1) ^ 1;
      #pragma unroll
      for (int jj = 0; jj < 8; ++jj) {
        u32 pr = (u32)((const u16*)&va)[jj] | ((u32)((const u16*)&vb)[jj] << 16);
        *(u32*)&VsT[nx][8 * sm + jj][(2 * sp) ^ ((jj ^ sm) << 3)] = pr;
      }
    }
    __syncthreads();
  };

  for (int kt = 0; kt < nkt; kt += 2) {   // manual 2-unroll: static reg dbuf
    body(kA, kB, kt);
    if (kt + 1 < nkt) body(kB, kA, kt + 1);
  }

  float ltot = lsum + __shfl_xor(lsum, 16);
  ltot += __shfl_xor(ltot, 32);
  const float inv = 1.0f / ltot;
  #pragma unroll
  for (int i = 0; i < 4; ++i) {
    const float invq = __shfl(inv, hi * 4 + i);
    const size_t row = (size_t)(b * 1024 + qr + hi * 4 + i);
    #pragma unroll
    for (int nb = 0; nb < 4; ++nb)
      O[row * 1024 + hcol + nb * 16 + ql] = f2bf(o[nb][i] * invq);
  }
}

// ---------------------------------------------------------------------------
extern "C" void kernel_launch(void* const* d_in, const int* in_sizes, int n_in,
                              void* d_out, int out_size, void* d_ws, size_t ws_size,
                              hipStream_t stream) {
  const float* dec  = (const float*)d_in[0];
  const float* enc  = (const float*)d_in[1];
  const float* sa_g = (const float*)d_in[4];
  const float* sa_b = (const float*)d_in[5];
  const float* sa_wq = (const float*)d_in[6];
  const float* sa_bq = (const float*)d_in[7];
  const float* sa_wk = (const float*)d_in[8];
  const float* sa_wv = (const float*)d_in[9];
  const float* sa_bv = (const float*)d_in[10];
  const float* sa_wo = (const float*)d_in[11];
  const float* sa_bo = (const float*)d_in[12];
  const float* ca_g = (const float*)d_in[13];
  const float* ca_b = (const float*)d_in[14];
  const float* ca_wq = (const float*)d_in[15];
  const float* ca_bq = (const float*)d_in[16];
  const float* ca_wk = (const float*)d_in[17];
  const float* ca_wv = (const float*)d_in[18];
  const float* ca_bv = (const float*)d_in[19];
  const float* ca_wo = (const float*)d_in[20];
  const float* ca_bo = (const float*)d_in[21];
  const float* mlp_g = (const float*)d_in[22];
  const float* mlp_b = (const float*)d_in[23];
  const float* w1 = (const float*)d_in[24];
  const float* b1 = (const float*)d_in[25];
  const float* w2 = (const float*)d_in[26];
  const float* b2 = (const float*)d_in[27];

  const size_t MB = 1024 * 1024;
  if (ws_size < 97 * MB) return;
  char* ws = (char*)d_ws;
  // persistent weights
  u16* WQKV = (u16*)(ws + 0 * MB);           // [3072][1024]
  u16* CQT  = (u16*)(ws + 6 * MB);           // [1024][1024]
  u16* CKV  = (u16*)(ws + 8 * MB);           // [2048][1024]
  u16* WOT  = (u16*)(ws + 12 * MB);
  u16* COT  = (u16*)(ws + 14 * MB);
  float* B3 = (float*)(ws + 16 * MB);        // 3072 f32
  float* B2 = (float*)(ws + 16 * MB + 16384);// 2048 f32
  // activations (aliased across stages)
  u16* XLN  = (u16*)(ws + 17 * MB);          // [4096][1024]
  u16* AO   = (u16*)(ws + 25 * MB);          // [4096][1024]; stage C: W1T
  u16* W1T  = (u16*)(ws + 25 * MB);          // [4096][1024] (stage C)
  u16* ENC  = (u16*)(ws + 33 * MB);          // [4096][1024]; stage C: part of H1
  u16* FB   = (u16*)(ws + 41 * MB);          // [4096][3072] (stage A)
  u16* EF   = (u16*)(ws + 41 * MB);          // [4096][2048] (stage B)
  u16* CQB  = (u16*)(ws + 57 * MB);          // [4096][1024] (stage B)
  u16* H1   = (u16*)(ws + 33 * MB);          // [4096][4096] (stage C, over ENC+FB)
  float* X1 = (float*)(ws + 65 * MB);        // [4096][1024] f32; stage C: W2T
  u16* W2T  = (u16*)(ws + 65 * MB);          // [1024][4096] (stage C)
  float* X2 = (float*)(ws + 81 * MB);        // [4096][1024] f32
  float* OUT = (float*)d_out;

  const dim3 blk(256), gblk(512), ablk(512);
  // ---- weight prep ----
  TC8 tc;
  tc.s[0] = sa_wq; tc.d[0] = WQKV;
  tc.s[1] = sa_wk; tc.d[1] = WQKV + 1024 * 1024;
  tc.s[2] = sa_wv; tc.d[2] = WQKV + 2048 * 1024;
  tc.s[3] = sa_wo; tc.d[3] = WOT;
  tc.s[4] = ca_wq; tc.d[4] = CQT;
  tc.s[5] = ca_wk; tc.d[5] = CKV;
  tc.s[6] = ca_wv; tc.d[6] = CKV + 1024 * 1024;
  tc.s[7] = ca_wo; tc.d[7] = COT;
  transcvt8_kernel<<<dim3(32, 32, 8), blk, 0, stream>>>(tc);
  pack_bias_kernel<<<dim3(20), blk, 0, stream>>>(sa_bq, sa_bv, ca_bv, B3, B2);
  cvt_kernel<<<dim3(4096), blk, 0, stream>>>(enc, ENC);

  // ---- self-attention block ----
  ln_kernel<<<dim3(4096), blk, 0, stream>>>(dec, sa_g, sa_b, XLN);
  gemm_kernel<false, false><<<dim3(24, 32), gblk, 0, stream>>>(XLN, WQKV, B3, nullptr, FB, 4096, 3072, 1024);
  attn_kernel<true><<<dim3(64, 8), ablk, 0, stream>>>(FB, 3072, FB + 1024, 3072, FB + 2048, 3072, AO);
  gemm_kernel<true, false><<<dim3(8, 32), gblk, 0, stream>>>(AO, WOT, sa_bo, dec, X1, 4096, 1024, 1024);

  // ---- cross-attention block ----
  ln_kernel<<<dim3(4096), blk, 0, stream>>>(X1, ca_g, ca_b, XLN);
  gemm_kernel<false, false><<<dim3(16, 32), gblk, 0, stream>>>(ENC, CKV, B2, nullptr, EF, 4096, 2048, 1024);
  gemm_kernel<false, false><<<dim3(8, 32), gblk, 0, stream>>>(XLN, CQT, ca_bq, nullptr, CQB, 4096, 1024, 1024);
  attn_kernel<false><<<dim3(64, 8), ablk, 0, stream>>>(CQB, 1024, EF, 2048, EF + 1024, 2048, AO);
  gemm_kernel<true, false><<<dim3(8, 32), gblk, 0, stream>>>(AO, COT, ca_bo, X1, X2, 4096, 1024, 1024);

  // ---- FFN block ----
  transcvt_kernel<<<dim3(128, 32), blk, 0, stream>>>(w1, W1T, 1024, 4096);
  transcvt_kernel<<<dim3(32, 128), blk, 0, stream>>>(w2, W2T, 4096, 1024);
  ln_kernel<<<dim3(4096), blk, 0, stream>>>(X2, mlp_g, mlp_b, XLN);
  gemm_kernel<false, true><<<dim3(32, 32), gblk, 0, stream>>>(XLN, W1T, b1, nullptr, H1, 4096, 4096, 1024);
  gemm_kernel<true, false><<<dim3(8, 32), gblk, 0, stream>>>(H1, W2T, b2, X2, OUT, 4096, 1024, 4096);
}